// Round 10
// baseline (166.375 us; speedup 1.0000x reference)
//
#include <hip/hip_runtime.h>
#include <hip/hip_bf16.h>
#include <cstdint>

typedef __attribute__((ext_vector_type(8))) short short8;
typedef __attribute__((ext_vector_type(4))) short short4v;
typedef __attribute__((ext_vector_type(4))) float f32x4;
typedef __attribute__((ext_vector_type(16))) float f32x16;
typedef __attribute__((ext_vector_type(4))) unsigned int u32x4;
typedef unsigned short ushort_t;
typedef unsigned int uint32;

#define DEVI static __device__ __forceinline__

DEVI ushort_t f2bf(float f){
  uint32 u = __builtin_bit_cast(uint32, f);
  u += 0x7FFFu + ((u >> 16) & 1u);
  return (ushort_t)(u >> 16);
}
DEVI uint32 cvtpk_bf16(float lo, float hi){
  uint32 r;
  asm("v_cvt_pk_bf16_f32 %0, %1, %2" : "=v"(r) : "v"(lo), "v"(hi));
  return r;
}
DEVI void plswap(uint32& a, uint32& b){
  asm("v_permlane32_swap_b32 %0, %1" : "+v"(a), "+v"(b));
}

typedef __attribute__((address_space(1))) const uint32 g_u32;
typedef __attribute__((address_space(3))) uint32 l_u32;
#define GL_LDS16(gp, lp) __builtin_amdgcn_global_load_lds((g_u32*)(gp), (l_u32*)(lp), 16, 0, 0)

#define MFMA16(a, b, c) __builtin_amdgcn_mfma_f32_16x16x32_bf16(a, b, c, 0, 0, 0)
#define MFMA32(a, b, c) __builtin_amdgcn_mfma_f32_32x32x16_bf16(a, b, c, 0, 0, 0)

// ---------------- fp32 -> bf16 conversion + rope table ----------------
__global__ __launch_bounds__(256) void convert_all(
    const float* __restrict__ x, const float* __restrict__ wq, const float* __restrict__ wk,
    const float* __restrict__ wv, const float* __restrict__ wo,
    ushort_t* __restrict__ xb, ushort_t* __restrict__ wqkv, ushort_t* __restrict__ wob,
    float2* __restrict__ tab){
  int bid = blockIdx.x;
  if (bid >= 6144){
    const int idx = (bid - 6144) * 256 + threadIdx.x;    // 65536
    const int tok = idx >> 5, j = idx & 31;
    const float theta = exp2f(-(float)j * 0.4152410118609203f);   // log2(10000)/32
    const float ang = (float)(tok + 1) * theta;
    float s, c;
    sincosf(ang, &s, &c);
    tab[idx] = make_float2(c, s);
    return;
  }
  const float* src; ushort_t* dst; long base;
  if (bid < 4096){ src = x; dst = xb; base = (long)bid * 2048; }
  else {
    int r = bid - 4096; int sel = r >> 9; int o = r & 511;
    src = sel==0?wq: sel==1?wk: sel==2?wv: wo;
    dst = (sel<3) ? (wqkv + (long)sel * 1048576) : wob;
    base = (long)o * 2048;
  }
  long i = base + (long)threadIdx.x * 8;
  const float* p = src + i;
  float4 a = *(const float4*)p;
  float4 b = *(const float4*)(p + 4);
  short8 v;
  v[0]=(short)f2bf(a.x); v[1]=(short)f2bf(a.y); v[2]=(short)f2bf(a.z); v[3]=(short)f2bf(a.w);
  v[4]=(short)f2bf(b.x); v[5]=(short)f2bf(b.y); v[6]=(short)f2bf(b.z); v[7]=(short)f2bf(b.w);
  *(short8*)(dst + i) = v;
}

// ---------------- QKV GEMM, 256x128 tile, BK=64, tri-buffered 2-phase ----------------
__global__ __launch_bounds__(512, 2) void gemm_qkv(
    const ushort_t* __restrict__ A, const ushort_t* __restrict__ Bw,
    const float* __restrict__ bq, const float* __restrict__ bk, const float* __restrict__ bv,
    const float2* __restrict__ tab,
    ushort_t* __restrict__ Qb, ushort_t* __restrict__ Kb, ushort_t* __restrict__ Vt){
  __shared__ __align__(16) ushort_t S[73728];   // 144 KB
  const int tid = threadIdx.x;
  const int w = tid >> 6, l = tid & 63, lr = l & 15, lg = l >> 4;
  const int wm = w >> 1, wn = w & 1;            // 4M x 2N
  const int xcd = blockIdx.x & 7;
  const int l9  = blockIdx.x >> 3;              // 0..95
  const int bg  = l9 >> 5;                      // 0..2
  const int rem = l9 & 31;
  const int bm  = ((xcd & 3) << 3) + (rem >> 2);
  const int bn  = ((xcd >> 2) * 12) + (bg << 2) + (rem & 3);
  const int m0 = bm << 8, n0 = bn << 7;
  const int rbase = tid >> 2;
  const int swzk = (tid & 3) ^ ((tid >> 3) & 3);
  const ushort_t* aS = A  + (long)(m0 + rbase) * 1024 + swzk * 8;
  const ushort_t* bS = Bw + (long)(n0 + rbase) * 1024 + swzk * 8;
  const int slot = (lg ^ ((lr >> 1) & 3)) << 3;
  const int arow = wm * 64 + lr;
  const int brow = wn * 64 + lr;
  f32x4 acc[4][4] = {};

#define STGA(kk, t, bf_) do{ \
    const ushort_t* _s = aS + (long)(t)*64 + (kk)*32; \
    ushort_t* _d = &S[(bf_)*24576 + (kk)*8192 + tid*8]; \
    GL_LDS16(_s,          _d); \
    GL_LDS16(_s + 131072, _d + 4096); }while(0)
#define STGB(kk, t, bf_) do{ \
    GL_LDS16(bS + (long)(t)*64 + (kk)*32, \
             &S[(bf_)*24576 + 16384 + (kk)*4096 + tid*8]); }while(0)

  STGA(0,0,0); STGB(0,0,0); STGA(1,0,0); STGB(1,0,0);
  STGA(0,1,1); STGB(0,1,1); STGA(1,1,1); STGB(1,1,1);
  asm volatile("s_waitcnt vmcnt(6)" ::: "memory");
  __builtin_amdgcn_s_barrier();

  int buf = 0;
  for (int t = 0; t < 16; ++t){
    const int nstg = (buf >= 1) ? buf - 1 : 2;
    const ushort_t* SA = &S[buf * 24576];
    const ushort_t* SB = &S[buf * 24576 + 16384];
    short8 af[4], bfv[4];
#pragma unroll
    for (int mi = 0; mi < 4; ++mi) af[mi]  = *(const short8*)&SA[(arow + mi*16)*32 + slot];
#pragma unroll
    for (int nc = 0; nc < 4; ++nc) bfv[nc] = *(const short8*)&SB[(brow + nc*16)*32 + slot];
    if (t < 14){ STGA(0, t+2, nstg); STGB(0, t+2, nstg); }
    __builtin_amdgcn_s_barrier();
    __builtin_amdgcn_s_setprio(1);
#pragma unroll
    for (int mi = 0; mi < 4; ++mi)
#pragma unroll
      for (int nc = 0; nc < 4; ++nc)
        acc[mi][nc] = MFMA16(af[mi], bfv[nc], acc[mi][nc]);
    __builtin_amdgcn_s_setprio(0);
    __builtin_amdgcn_s_barrier();
#pragma unroll
    for (int mi = 0; mi < 4; ++mi) af[mi]  = *(const short8*)&SA[8192 + (arow + mi*16)*32 + slot];
#pragma unroll
    for (int nc = 0; nc < 4; ++nc) bfv[nc] = *(const short8*)&SB[4096 + (brow + nc*16)*32 + slot];
    if (t < 14){ STGA(1, t+2, nstg); STGB(1, t+2, nstg); }
    __builtin_amdgcn_s_barrier();
    __builtin_amdgcn_s_setprio(1);
#pragma unroll
    for (int mi = 0; mi < 4; ++mi)
#pragma unroll
      for (int nc = 0; nc < 4; ++nc)
        acc[mi][nc] = MFMA16(af[mi], bfv[nc], acc[mi][nc]);
    __builtin_amdgcn_s_setprio(0);
    if (t < 14)       asm volatile("s_waitcnt vmcnt(6)" ::: "memory");
    else if (t == 14) asm volatile("s_waitcnt vmcnt(0)" ::: "memory");
    __builtin_amdgcn_s_barrier();
    buf = (buf >= 2) ? 0 : buf + 1;
  }
#undef STGA
#undef STGB

  const int colX = n0 + (wn << 6);
  const int sel = colX >> 10;                // 0=Q 1=K 2=V
  const int h = (colX >> 6) & 15;
  const int cB = (colX & 1023) + lr;
  if (sel < 2){
    ushort_t* dst = sel ? Kb : Qb;
    const float* bp = sel ? bk : bq;
    const float bvs[4] = {bp[cB], bp[cB+16], bp[cB+32], bp[cB+48]};
#pragma unroll
    for (int mi = 0; mi < 4; ++mi){
      const int row0 = m0 + (wm << 6) + mi*16 + lg*4;
#pragma unroll
      for (int i = 0; i < 4; ++i){
        const int r = row0 + i;
        const int b = r >> 11, tok = r & 2047;
#pragma unroll
        for (int nc = 0; nc < 2; ++nc){
          const int j = nc*16 + lr;
          const float2 cs = tab[tok*32 + j];
          const float v0 = acc[mi][nc][i]   + bvs[nc];
          const float v1 = acc[mi][nc+2][i] + bvs[nc+2];
          const long base = (((long)((b<<4) + h) * 2048 + tok) << 6) + j;
          dst[base]      = f2bf(v0 * cs.x - v1 * cs.y);
          dst[base + 32] = f2bf(v1 * cs.x + v0 * cs.y);
        }
      }
    }
  } else {
    const float bvs[4] = {bv[cB], bv[cB+16], bv[cB+32], bv[cB+48]};
#pragma unroll
    for (int mi = 0; mi < 4; ++mi){
      const int row0 = m0 + (wm << 6) + mi*16 + lg*4;
#pragma unroll
      for (int nc = 0; nc < 4; ++nc){
        const int d = nc*16 + lr;
#pragma unroll
        for (int i = 0; i < 4; ++i){
          const int r = row0 + i;
          const int b = r >> 11, tok = r & 2047;
          Vt[((long)((b<<4) + h) * 64 + d) * 2048 + tok] = f2bf(acc[mi][nc][i] + bvs[nc]);
        }
      }
    }
  }
}

// ---------------- output GEMM, 256x128, BK=64, tri-buffered (fp32 out) ----------------
__global__ __launch_bounds__(512, 2) void gemm_out(
    const ushort_t* __restrict__ A, const ushort_t* __restrict__ Bw,
    const float* __restrict__ bias, float* __restrict__ Cout){
  __shared__ __align__(16) ushort_t S[73728];   // 144 KB
  const int tid = threadIdx.x;
  const int w = tid >> 6, l = tid & 63, lr = l & 15, lg = l >> 4;
  const int wm = w >> 1, wn = w & 1;
  const int xcd = blockIdx.x & 7;
  const int l9  = blockIdx.x >> 3;              // 0..31
  const int bm  = (xcd << 2) + (l9 >> 3);
  const int bn  = l9 & 7;
  const int m0 = bm << 8, n0 = bn << 7;
  const int rbase = tid >> 2;
  const int swzk = (tid & 3) ^ ((tid >> 3) & 3);
  const ushort_t* aS = A  + (long)(m0 + rbase) * 1024 + swzk * 8;
  const ushort_t* bS = Bw + (long)(n0 + rbase) * 1024 + swzk * 8;
  const int slot = (lg ^ ((lr >> 1) & 3)) << 3;
  const int arow = wm * 64 + lr;
  const int brow = wn * 64 + lr;
  f32x4 acc[4][4] = {};

#define STGA(kk, t, bf_) do{ \
    const ushort_t* _s = aS + (long)(t)*64 + (kk)*32; \
    ushort_t* _d = &S[(bf_)*24576 + (kk)*8192 + tid*8]; \
    GL_LDS16(_s,          _d); \
    GL_LDS16(_s + 131072, _d + 4096); }while(0)
#define STGB(kk, t, bf_) do{ \
    GL_LDS16(bS + (long)(t)*64 + (kk)*32, \
             &S[(bf_)*24576 + 16384 + (kk)*4096 + tid*8]); }while(0)

  STGA(0,0,0); STGB(0,0,0); STGA(1,0,0); STGB(1,0,0);
  STGA(0,1,1); STGB(0,1,1); STGA(1,1,1); STGB(1,1,1);
  asm volatile("s_waitcnt vmcnt(6)" ::: "memory");
  __builtin_amdgcn_s_barrier();

  int buf = 0;
  for (int t = 0; t < 16; ++t){
    const int nstg = (buf >= 1) ? buf - 1 : 2;
    const ushort_t* SA = &S[buf * 24576];
    const ushort_t* SB = &S[buf * 24576 + 16384];
    short8 af[4], bfv[4];
#pragma unroll
    for (int mi = 0; mi < 4; ++mi) af[mi]  = *(const short8*)&SA[(arow + mi*16)*32 + slot];
#pragma unroll
    for (int nc = 0; nc < 4; ++nc) bfv[nc] = *(const short8*)&SB[(brow + nc*16)*32 + slot];
    if (t < 14){ STGA(0, t+2, nstg); STGB(0, t+2, nstg); }
    __builtin_amdgcn_s_barrier();
    __builtin_amdgcn_s_setprio(1);
#pragma unroll
    for (int mi = 0; mi < 4; ++mi)
#pragma unroll
      for (int nc = 0; nc < 4; ++nc)
        acc[mi][nc] = MFMA16(af[mi], bfv[nc], acc[mi][nc]);
    __builtin_amdgcn_s_setprio(0);
    __builtin_amdgcn_s_barrier();
#pragma unroll
    for (int mi = 0; mi < 4; ++mi) af[mi]  = *(const short8*)&SA[8192 + (arow + mi*16)*32 + slot];
#pragma unroll
    for (int nc = 0; nc < 4; ++nc) bfv[nc] = *(const short8*)&SB[4096 + (brow + nc*16)*32 + slot];
    if (t < 14){ STGA(1, t+2, nstg); STGB(1, t+2, nstg); }
    __builtin_amdgcn_s_barrier();
    __builtin_amdgcn_s_setprio(1);
#pragma unroll
    for (int mi = 0; mi < 4; ++mi)
#pragma unroll
      for (int nc = 0; nc < 4; ++nc)
        acc[mi][nc] = MFMA16(af[mi], bfv[nc], acc[mi][nc]);
    __builtin_amdgcn_s_setprio(0);
    if (t < 14)       asm volatile("s_waitcnt vmcnt(6)" ::: "memory");
    else if (t == 14) asm volatile("s_waitcnt vmcnt(0)" ::: "memory");
    __builtin_amdgcn_s_barrier();
    buf = (buf >= 2) ? 0 : buf + 1;
  }
#undef STGA
#undef STGB

  const int colBase = n0 + (wn << 6) + lr;
#pragma unroll
  for (int mi = 0; mi < 4; ++mi){
    const int row0 = m0 + (wm << 6) + mi*16 + lg*4;
#pragma unroll
    for (int nc = 0; nc < 4; ++nc){
      const int col = colBase + nc*16;
      const float bvv = bias[col];
#pragma unroll
      for (int i = 0; i < 4; ++i)
        Cout[(long)(row0 + i) * 1024 + col] = acc[mi][nc][i] + bvv;
    }
  }
}

// ---------------- flash attention (causal), 4-wave block, 64 q-rows/wave, KBLK=64 ----------------
// Each wave owns TWO 32-q chunks (qa, qb) sharing all K/V fragment reads:
// per 32-k subtile 8 ds_read feed 16 MFMA (was 1:1). KBLK=64 halves barriers.
// K LDS [64 krow][64 d], V LDS [64 d][64 k], both 16B-chunk XOR (row&7) on
// staging source AND read (rule #21). Counted vmcnt(4), 2 blocks/CU paired heavy+light.
__global__ __launch_bounds__(256, 2) void attn(
    const ushort_t* __restrict__ Qb, const ushort_t* __restrict__ Kb,
    const ushort_t* __restrict__ Vt, ushort_t* __restrict__ yb){
  __shared__ __align__(16) ushort_t Ks[2][4096];
  __shared__ __align__(16) ushort_t Vs[2][4096];
  const int tid = threadIdx.x;
  const int w = tid >> 6, l = tid & 63;
  const int lq = l & 31, hi = l >> 5;
  const int xcd = blockIdx.x & 7;
  const int idx = blockIdx.x >> 3;          // 0..63
  const int hi5 = idx >> 5;                 // 0/1
  const int bh  = (xcd << 3) + ((idx >> 3) & 3) + hi5 * 4;
  const int slab = hi5 ? (idx & 7) : 7 - (idx & 7);
  const int wkt  = slab * 4 + w;            // wave's diagonal 64-k tile
  const int ktmax = slab * 4 + 3;
  const int qa = slab * 8 + 2 * w;          // two q-chunks per wave
  const ushort_t* Qh  = Qb + (long)bh * 131072;
  const ushort_t* Kh  = Kb + (long)bh * 131072;
  const ushort_t* Vth = Vt + (long)bh * 131072;
  const int h8 = hi * 8;

  // Q fragments for both chunks (persistent)
  short8 qfa[4], qfb[4];
  {
    const ushort_t* qpa = &Qh[(long)(qa * 32 + lq) * 64 + h8];
    const ushort_t* qpb = qpa + 2048;   // +32 rows
#pragma unroll
    for (int f = 0; f < 4; ++f){
      qfa[f] = *(const short8*)(qpa + f * 16);
      qfb[f] = *(const short8*)(qpb + f * 16);
    }
  }

  // staging: per thread 2 K + 2 V 16B chunks. row0 = 8w + l>>3 (0..31), row1 = +32.
  const int r0 = (w << 3) + (l >> 3);
  const int r1 = r0 + 32;
  const long ksrc0 = ((long)r0 << 6) + (((l & 7) ^ (r0 & 7)) << 3);
  const long ksrc1 = ((long)r1 << 6) + (((l & 7) ^ (r1 & 7)) << 3);
  const long vsrc0 = ((long)r0 << 11) + (((l & 7) ^ (r0 & 7)) << 3);
  const long vsrc1 = ((long)r1 << 11) + (((l & 7) ^ (r1 & 7)) << 3);
  const int dst0 = (w << 9) + (l << 3);
  const int dst1 = 2048 + dst0;

  f32x16 oa0 = {}, oa1 = {}, ob0 = {}, ob1 = {};
  float lsa = 0.f, lsb = 0.f;
  const float cl2 = 0.1803368801111204f;   // log2(e)/8

  // prologue: stage tile 0 into buf 0 (drained by loop's vmcnt(4))
  GL_LDS16(Kh + ksrc0,  &Ks[0][dst0]);
  GL_LDS16(Kh + ksrc1,  &Ks[0][dst1]);
  GL_LDS16(Vth + vsrc0, &Vs[0][dst0]);
  GL_LDS16(Vth + vsrc1, &Vs[0][dst1]);

  int cur = 0;
  for (int kt = 0; kt <= ktmax; ++kt){
    if (kt < ktmax){
      const long k0n = (long)(kt + 1) << 6;
      GL_LDS16(Kh + k0n * 64 + ksrc0,  &Ks[cur ^ 1][dst0]);
      GL_LDS16(Kh + k0n * 64 + ksrc1,  &Ks[cur ^ 1][dst1]);
      GL_LDS16(Vth + k0n + vsrc0,      &Vs[cur ^ 1][dst0]);
      GL_LDS16(Vth + k0n + vsrc1,      &Vs[cur ^ 1][dst1]);
      asm volatile("s_waitcnt vmcnt(4)" ::: "memory");   // tile kt resident
    } else {
      asm volatile("s_waitcnt vmcnt(0)" ::: "memory");
    }
    __builtin_amdgcn_s_barrier();
    if (kt <= wkt){
      const bool diag = (kt == wkt);
      const int swl = lq & 7;
#pragma unroll
      for (int ksub = 0; ksub < 2; ++ksub){
        // K fragments: rows ksub*32+lq, d-chunks (f*2+hi)^swl
        const ushort_t* kr = &Ks[cur][(ksub * 32 + lq) << 6];
        short8 kf0 = *(const short8*)&kr[(((0 << 1) + hi) ^ swl) << 3];
        short8 kf1 = *(const short8*)&kr[(((1 << 1) + hi) ^ swl) << 3];
        short8 kf2 = *(const short8*)&kr[(((2 << 1) + hi) ^ swl) << 3];
        short8 kf3 = *(const short8*)&kr[(((3 << 1) + hi) ^ swl) << 3];
        // S^T for both q-chunks
        f32x16 sa = {}, sb = {};
        sa = MFMA32(kf0, qfa[0], sa); sb = MFMA32(kf0, qfb[0], sb);
        sa = MFMA32(kf1, qfa[1], sa); sb = MFMA32(kf1, qfb[1], sb);
        sa = MFMA32(kf2, qfa[2], sa); sb = MFMA32(kf2, qfb[2], sb);
        sa = MFMA32(kf3, qfa[3], sa); sb = MFMA32(kf3, qfb[3], sb);
        if (diag){
          if (ksub == 0){
            // k in [qa*32, +31]: mask sa triangular; sb unmasked
#pragma unroll
            for (int r = 0; r < 16; ++r){
              const int rk = (r & 3) + 8 * (r >> 2) + 4 * hi;
              if (rk > lq) sa[r] = -1e30f;
            }
          } else {
            // k in [qb*32, +31]: sa fully masked; sb triangular
#pragma unroll
            for (int r = 0; r < 16; ++r){
              const int rk = (r & 3) + 8 * (r >> 2) + 4 * hi;
              sa[r] = -1e30f;
              if (rk > lq) sb[r] = -1e30f;
            }
          }
        }
#pragma unroll
        for (int r = 0; r < 16; ++r){
          sa[r] = __builtin_amdgcn_exp2f(__builtin_fmaf(sa[r], cl2, -2.0f));
          sb[r] = __builtin_amdgcn_exp2f(__builtin_fmaf(sb[r], cl2, -2.0f));
        }
        {
          float t0 = (sa[0]+sa[1])+(sa[2]+sa[3]), t1 = (sa[4]+sa[5])+(sa[6]+sa[7]);
          float t2 = (sa[8]+sa[9])+(sa[10]+sa[11]), t3 = (sa[12]+sa[13])+(sa[14]+sa[15]);
          lsa += (t0 + t1) + (t2 + t3);
          float u0 = (sb[0]+sb[1])+(sb[2]+sb[3]), u1 = (sb[4]+sb[5])+(sb[6]+sb[7]);
          float u2 = (sb[8]+sb[9])+(sb[10]+sb[11]), u3 = (sb[12]+sb[13])+(sb[14]+sb[15]);
          lsb += (u0 + u1) + (u2 + u3);
        }
        // pack P^T -> bf16 B-frags (chunk a)
        uint32 a0 = cvtpk_bf16(sa[0], sa[1]),   c0 = cvtpk_bf16(sa[4], sa[5]);
        uint32 a1 = cvtpk_bf16(sa[2], sa[3]),   c1 = cvtpk_bf16(sa[6], sa[7]);
        uint32 a2 = cvtpk_bf16(sa[8], sa[9]),   c2 = cvtpk_bf16(sa[12], sa[13]);
        uint32 a3 = cvtpk_bf16(sa[10], sa[11]), c3 = cvtpk_bf16(sa[14], sa[15]);
        plswap(a0, c0); plswap(a1, c1); plswap(a2, c2); plswap(a3, c3);
        u32x4 pca0 = {a0, a1, c0, c1};
        u32x4 pca1 = {a2, a3, c2, c3};
        short8 pa0 = __builtin_bit_cast(short8, pca0);
        short8 pa1 = __builtin_bit_cast(short8, pca1);
        // pack chunk b
        uint32 d0 = cvtpk_bf16(sb[0], sb[1]),   e0 = cvtpk_bf16(sb[4], sb[5]);
        uint32 d1 = cvtpk_bf16(sb[2], sb[3]),   e1 = cvtpk_bf16(sb[6], sb[7]);
        uint32 d2 = cvtpk_bf16(sb[8], sb[9]),   e2 = cvtpk_bf16(sb[12], sb[13]);
        uint32 d3 = cvtpk_bf16(sb[10], sb[11]), e3 = cvtpk_bf16(sb[14], sb[15]);
        plswap(d0, e0); plswap(d1, e1); plswap(d2, e2); plswap(d3, e3);
        u32x4 pcb0 = {d0, d1, e0, e1};
        u32x4 pcb1 = {d2, d3, e2, e3};
        short8 pb0 = __builtin_bit_cast(short8, pcb0);
        short8 pb1 = __builtin_bit_cast(short8, pcb1);
        // V fragments: d-rows lq / lq+32; k-chunks (ksub*4 + kh*2 + hi)^swl
        const ushort_t* vrlo = &Vs[cur][lq << 6];
        const ushort_t* vrhi = &Vs[cur][(lq + 32) << 6];
        const int cbase = ksub << 2;
        short8 vf00 = *(const short8*)&vrlo[((cbase + hi    ) ^ swl) << 3];
        short8 vf01 = *(const short8*)&vrlo[((cbase + 2 + hi) ^ swl) << 3];
        short8 vf10 = *(const short8*)&vrhi[((cbase + hi    ) ^ swl) << 3];
        short8 vf11 = *(const short8*)&vrhi[((cbase + 2 + hi) ^ swl) << 3];
        // O^T += V^T P^T for both chunks
        oa0 = MFMA32(vf00, pa0, oa0); oa0 = MFMA32(vf01, pa1, oa0);
        oa1 = MFMA32(vf10, pa0, oa1); oa1 = MFMA32(vf11, pa1, oa1);
        ob0 = MFMA32(vf00, pb0, ob0); ob0 = MFMA32(vf01, pb1, ob0);
        ob1 = MFMA32(vf10, pb0, ob1); ob1 = MFMA32(vf11, pb1, ob1);
      }
    }
    __builtin_amdgcn_s_barrier();
    cur ^= 1;
  }
  lsa += __shfl_xor(lsa, 32);
  lsb += __shfl_xor(lsb, 32);
  const float inva = 1.0f / lsa;
  const float invb = 1.0f / lsb;
  const int b = bh >> 4, h = bh & 15;
  {
    const int tok = qa * 32 + lq;
    ushort_t* yrow = yb + (long)(b * 2048 + tok) * 1024 + h * 64;
#pragma unroll
    for (int g = 0; g < 4; ++g){
      short4v p0, p1;
#pragma unroll
      for (int j = 0; j < 4; ++j){
        p0[j] = (short)f2bf(oa0[4*g + j] * inva);
        p1[j] = (short)f2bf(oa1[4*g + j] * inva);
      }
      *(short4v*)&yrow[8*g + 4*hi]      = p0;
      *(short4v*)&yrow[32 + 8*g + 4*hi] = p1;
    }
  }
  {
    const int tok = qa * 32 + 32 + lq;
    ushort_t* yrow = yb + (long)(b * 2048 + tok) * 1024 + h * 64;
#pragma unroll
    for (int g = 0; g < 4; ++g){
      short4v p0, p1;
#pragma unroll
      for (int j = 0; j < 4; ++j){
        p0[j] = (short)f2bf(ob0[4*g + j] * invb);
        p1[j] = (short)f2bf(ob1[4*g + j] * invb);
      }
      *(short4v*)&yrow[8*g + 4*hi]      = p0;
      *(short4v*)&yrow[32 + 8*g + 4*hi] = p1;
    }
  }
}

// ---------------- launch ----------------
extern "C" void kernel_launch(void* const* d_in, const int* in_sizes, int n_in,
                              void* d_out, int out_size, void* d_ws, size_t ws_size,
                              hipStream_t stream){
  const float* x  = (const float*)d_in[0];
  const float* Wq = (const float*)d_in[1];
  const float* bq = (const float*)d_in[2];
  const float* Wk = (const float*)d_in[3];
  const float* bk = (const float*)d_in[4];
  const float* Wv = (const float*)d_in[5];
  const float* bv = (const float*)d_in[6];
  const float* Wo = (const float*)d_in[7];
  const float* bo = (const float*)d_in[8];
  char* ws = (char*)d_ws;
  ushort_t* xb   = (ushort_t*)(ws);                      // 16 MB; reused as yb after attn
  ushort_t* wqkv = (ushort_t*)(ws + 16777216);           // 6 MB (Q,K,V packed)
  ushort_t* wob  = (ushort_t*)(ws + 23068672);           // 2 MB
  float2*   tab  = (float2*)  (ws + 25165824);           // 512 KB
  ushort_t* Qb   = (ushort_t*)(ws + 25690112);           // 16 MB
  ushort_t* Kb   = (ushort_t*)(ws + 42467328);           // 16 MB
  ushort_t* Vt   = (ushort_t*)(ws + 59244544);           // 16 MB
  ushort_t* yb   = xb;

  convert_all<<<6400, 256, 0, stream>>>(x, Wq, Wk, Wv, Wo, xb, wqkv, wob, tab);
  gemm_qkv<<<768, 512, 0, stream>>>(xb, wqkv, bq, bk, bv, tab, Qb, Kb, Vt);
  attn<<<512, 256, 0, stream>>>(Qb, Kb, Vt, yb);
  gemm_out<<<256, 512, 0, stream>>>(yb, wob, bo, (float*)d_out);
}

// Round 11
// 158.358 us; speedup vs baseline: 1.0506x; 1.0506x over previous
//
#include <hip/hip_runtime.h>
#include <hip/hip_bf16.h>
#include <cstdint>

typedef __attribute__((ext_vector_type(8))) short short8;
typedef __attribute__((ext_vector_type(4))) short short4v;
typedef __attribute__((ext_vector_type(4))) float f32x4;
typedef __attribute__((ext_vector_type(16))) float f32x16;
typedef __attribute__((ext_vector_type(4))) unsigned int u32x4;
typedef unsigned short ushort_t;
typedef unsigned int uint32;

#define DEVI static __device__ __forceinline__

DEVI ushort_t f2bf(float f){
  uint32 u = __builtin_bit_cast(uint32, f);
  u += 0x7FFFu + ((u >> 16) & 1u);
  return (ushort_t)(u >> 16);
}
DEVI uint32 cvtpk_bf16(float lo, float hi){
  uint32 r;
  asm("v_cvt_pk_bf16_f32 %0, %1, %2" : "=v"(r) : "v"(lo), "v"(hi));
  return r;
}
DEVI void plswap(uint32& a, uint32& b){
  asm("v_permlane32_swap_b32 %0, %1" : "+v"(a), "+v"(b));
}

typedef __attribute__((address_space(1))) const uint32 g_u32;
typedef __attribute__((address_space(3))) uint32 l_u32;
#define GL_LDS16(gp, lp) __builtin_amdgcn_global_load_lds((g_u32*)(gp), (l_u32*)(lp), 16, 0, 0)

#define MFMA16(a, b, c) __builtin_amdgcn_mfma_f32_16x16x32_bf16(a, b, c, 0, 0, 0)
#define MFMA32(a, b, c) __builtin_amdgcn_mfma_f32_32x32x16_bf16(a, b, c, 0, 0, 0)

// ---------------- fp32 -> bf16 conversion + rope table ----------------
__global__ __launch_bounds__(256) void convert_all(
    const float* __restrict__ x, const float* __restrict__ wq, const float* __restrict__ wk,
    const float* __restrict__ wv, const float* __restrict__ wo,
    ushort_t* __restrict__ xb, ushort_t* __restrict__ wqkv, ushort_t* __restrict__ wob,
    float2* __restrict__ tab){
  int bid = blockIdx.x;
  if (bid >= 6144){
    const int idx = (bid - 6144) * 256 + threadIdx.x;    // 65536
    const int tok = idx >> 5, j = idx & 31;
    const float theta = exp2f(-(float)j * 0.4152410118609203f);   // log2(10000)/32
    const float ang = (float)(tok + 1) * theta;
    float s, c;
    sincosf(ang, &s, &c);
    tab[idx] = make_float2(c, s);
    return;
  }
  const float* src; ushort_t* dst; long base;
  if (bid < 4096){ src = x; dst = xb; base = (long)bid * 2048; }
  else {
    int r = bid - 4096; int sel = r >> 9; int o = r & 511;
    src = sel==0?wq: sel==1?wk: sel==2?wv: wo;
    dst = (sel<3) ? (wqkv + (long)sel * 1048576) : wob;
    base = (long)o * 2048;
  }
  long i = base + (long)threadIdx.x * 8;
  const float* p = src + i;
  float4 a = *(const float4*)p;
  float4 b = *(const float4*)(p + 4);
  short8 v;
  v[0]=(short)f2bf(a.x); v[1]=(short)f2bf(a.y); v[2]=(short)f2bf(a.z); v[3]=(short)f2bf(a.w);
  v[4]=(short)f2bf(b.x); v[5]=(short)f2bf(b.y); v[6]=(short)f2bf(b.z); v[7]=(short)f2bf(b.w);
  *(short8*)(dst + i) = v;
}

// ---------------- QKV GEMM, 256x128 tile, BK=64, tri-buffered 2-phase ----------------
__global__ __launch_bounds__(512, 2) void gemm_qkv(
    const ushort_t* __restrict__ A, const ushort_t* __restrict__ Bw,
    const float* __restrict__ bq, const float* __restrict__ bk, const float* __restrict__ bv,
    const float2* __restrict__ tab,
    ushort_t* __restrict__ Qb, ushort_t* __restrict__ Kb, ushort_t* __restrict__ Vt){
  __shared__ __align__(16) ushort_t S[73728];   // 144 KB
  const int tid = threadIdx.x;
  const int w = tid >> 6, l = tid & 63, lr = l & 15, lg = l >> 4;
  const int wm = w >> 1, wn = w & 1;            // 4M x 2N
  const int xcd = blockIdx.x & 7;
  const int l9  = blockIdx.x >> 3;              // 0..95
  const int bg  = l9 >> 5;                      // 0..2
  const int rem = l9 & 31;
  const int bm  = ((xcd & 3) << 3) + (rem >> 2);
  const int bn  = ((xcd >> 2) * 12) + (bg << 2) + (rem & 3);
  const int m0 = bm << 8, n0 = bn << 7;
  const int rbase = tid >> 2;
  const int swzk = (tid & 3) ^ ((tid >> 3) & 3);
  const ushort_t* aS = A  + (long)(m0 + rbase) * 1024 + swzk * 8;
  const ushort_t* bS = Bw + (long)(n0 + rbase) * 1024 + swzk * 8;
  const int slot = (lg ^ ((lr >> 1) & 3)) << 3;
  const int arow = wm * 64 + lr;
  const int brow = wn * 64 + lr;
  f32x4 acc[4][4] = {};

#define STGA(kk, t, bf_) do{ \
    const ushort_t* _s = aS + (long)(t)*64 + (kk)*32; \
    ushort_t* _d = &S[(bf_)*24576 + (kk)*8192 + tid*8]; \
    GL_LDS16(_s,          _d); \
    GL_LDS16(_s + 131072, _d + 4096); }while(0)
#define STGB(kk, t, bf_) do{ \
    GL_LDS16(bS + (long)(t)*64 + (kk)*32, \
             &S[(bf_)*24576 + 16384 + (kk)*4096 + tid*8]); }while(0)

  STGA(0,0,0); STGB(0,0,0); STGA(1,0,0); STGB(1,0,0);
  STGA(0,1,1); STGB(0,1,1); STGA(1,1,1); STGB(1,1,1);
  asm volatile("s_waitcnt vmcnt(6)" ::: "memory");
  __builtin_amdgcn_s_barrier();

  int buf = 0;
  for (int t = 0; t < 16; ++t){
    const int nstg = (buf >= 1) ? buf - 1 : 2;
    const ushort_t* SA = &S[buf * 24576];
    const ushort_t* SB = &S[buf * 24576 + 16384];
    short8 af[4], bfv[4];
#pragma unroll
    for (int mi = 0; mi < 4; ++mi) af[mi]  = *(const short8*)&SA[(arow + mi*16)*32 + slot];
#pragma unroll
    for (int nc = 0; nc < 4; ++nc) bfv[nc] = *(const short8*)&SB[(brow + nc*16)*32 + slot];
    if (t < 14){ STGA(0, t+2, nstg); STGB(0, t+2, nstg); }
    __builtin_amdgcn_s_barrier();
    __builtin_amdgcn_s_setprio(1);
#pragma unroll
    for (int mi = 0; mi < 4; ++mi)
#pragma unroll
      for (int nc = 0; nc < 4; ++nc)
        acc[mi][nc] = MFMA16(af[mi], bfv[nc], acc[mi][nc]);
    __builtin_amdgcn_s_setprio(0);
    __builtin_amdgcn_s_barrier();
#pragma unroll
    for (int mi = 0; mi < 4; ++mi) af[mi]  = *(const short8*)&SA[8192 + (arow + mi*16)*32 + slot];
#pragma unroll
    for (int nc = 0; nc < 4; ++nc) bfv[nc] = *(const short8*)&SB[4096 + (brow + nc*16)*32 + slot];
    if (t < 14){ STGA(1, t+2, nstg); STGB(1, t+2, nstg); }
    __builtin_amdgcn_s_barrier();
    __builtin_amdgcn_s_setprio(1);
#pragma unroll
    for (int mi = 0; mi < 4; ++mi)
#pragma unroll
      for (int nc = 0; nc < 4; ++nc)
        acc[mi][nc] = MFMA16(af[mi], bfv[nc], acc[mi][nc]);
    __builtin_amdgcn_s_setprio(0);
    if (t < 14)       asm volatile("s_waitcnt vmcnt(6)" ::: "memory");
    else if (t == 14) asm volatile("s_waitcnt vmcnt(0)" ::: "memory");
    __builtin_amdgcn_s_barrier();
    buf = (buf >= 2) ? 0 : buf + 1;
  }
#undef STGA
#undef STGB

  const int colX = n0 + (wn << 6);
  const int sel = colX >> 10;                // 0=Q 1=K 2=V
  const int h = (colX >> 6) & 15;
  const int cB = (colX & 1023) + lr;
  if (sel < 2){
    ushort_t* dst = sel ? Kb : Qb;
    const float* bp = sel ? bk : bq;
    const float bvs[4] = {bp[cB], bp[cB+16], bp[cB+32], bp[cB+48]};
#pragma unroll
    for (int mi = 0; mi < 4; ++mi){
      const int row0 = m0 + (wm << 6) + mi*16 + lg*4;
#pragma unroll
      for (int i = 0; i < 4; ++i){
        const int r = row0 + i;
        const int b = r >> 11, tok = r & 2047;
#pragma unroll
        for (int nc = 0; nc < 2; ++nc){
          const int j = nc*16 + lr;
          const float2 cs = tab[tok*32 + j];
          const float v0 = acc[mi][nc][i]   + bvs[nc];
          const float v1 = acc[mi][nc+2][i] + bvs[nc+2];
          const long base = (((long)((b<<4) + h) * 2048 + tok) << 6) + j;
          dst[base]      = f2bf(v0 * cs.x - v1 * cs.y);
          dst[base + 32] = f2bf(v1 * cs.x + v0 * cs.y);
        }
      }
    }
  } else {
    // V: LDS transpose -> coalesced Vt writes (16B/lane, 8 lanes per 128B row)
    const float bvs[4] = {bv[cB], bv[cB+16], bv[cB+32], bv[cB+48]};
    ushort_t* T = &S[w * 4608];          // wave-private [64 d][72] bf16
#pragma unroll
    for (int nc = 0; nc < 4; ++nc){
      const int d = nc*16 + lr;
      const int dx = d & 7;
#pragma unroll
      for (int mi = 0; mi < 4; ++mi){
        const int col = mi*16 + lg*4;
        const int scol = (((col >> 3) ^ dx) << 3) + (col & 7);
        const uint32 p0 = cvtpk_bf16(acc[mi][nc][0] + bvs[nc], acc[mi][nc][1] + bvs[nc]);
        const uint32 p1 = cvtpk_bf16(acc[mi][nc][2] + bvs[nc], acc[mi][nc][3] + bvs[nc]);
        uint32* dp = (uint32*)&T[d*72 + scol];
        dp[0] = p0; dp[1] = p1;
      }
    }
    // wave-private region: no barrier needed; compiler waits lgkmcnt before reads
    const int rowbase = m0 + (wm << 6);
    const int b = rowbase >> 11;
    const int tok0 = rowbase & 2047;
    ushort_t* vbase = Vt + (((long)((b << 4) + h)) << 17);   // *64*2048
    const int dl = l >> 3, c8 = l & 7;
#pragma unroll
    for (int it = 0; it < 8; ++it){
      const int d = dl + it*8;
      short8 v = *(const short8*)&T[d*72 + ((c8 ^ (d & 7)) << 3)];
      *(short8*)&vbase[((long)d << 11) + tok0 + (c8 << 3)] = v;
    }
  }
}

// ---------------- output GEMM, 256x128, BK=64, tri-buffered (fp32 out) ----------------
__global__ __launch_bounds__(512, 2) void gemm_out(
    const ushort_t* __restrict__ A, const ushort_t* __restrict__ Bw,
    const float* __restrict__ bias, float* __restrict__ Cout){
  __shared__ __align__(16) ushort_t S[73728];   // 144 KB
  const int tid = threadIdx.x;
  const int w = tid >> 6, l = tid & 63, lr = l & 15, lg = l >> 4;
  const int wm = w >> 1, wn = w & 1;
  const int xcd = blockIdx.x & 7;
  const int l9  = blockIdx.x >> 3;              // 0..31
  const int bm  = (xcd << 2) + (l9 >> 3);
  const int bn  = l9 & 7;
  const int m0 = bm << 8, n0 = bn << 7;
  const int rbase = tid >> 2;
  const int swzk = (tid & 3) ^ ((tid >> 3) & 3);
  const ushort_t* aS = A  + (long)(m0 + rbase) * 1024 + swzk * 8;
  const ushort_t* bS = Bw + (long)(n0 + rbase) * 1024 + swzk * 8;
  const int slot = (lg ^ ((lr >> 1) & 3)) << 3;
  const int arow = wm * 64 + lr;
  const int brow = wn * 64 + lr;
  f32x4 acc[4][4] = {};

#define STGA(kk, t, bf_) do{ \
    const ushort_t* _s = aS + (long)(t)*64 + (kk)*32; \
    ushort_t* _d = &S[(bf_)*24576 + (kk)*8192 + tid*8]; \
    GL_LDS16(_s,          _d); \
    GL_LDS16(_s + 131072, _d + 4096); }while(0)
#define STGB(kk, t, bf_) do{ \
    GL_LDS16(bS + (long)(t)*64 + (kk)*32, \
             &S[(bf_)*24576 + 16384 + (kk)*4096 + tid*8]); }while(0)

  STGA(0,0,0); STGB(0,0,0); STGA(1,0,0); STGB(1,0,0);
  STGA(0,1,1); STGB(0,1,1); STGA(1,1,1); STGB(1,1,1);
  asm volatile("s_waitcnt vmcnt(6)" ::: "memory");
  __builtin_amdgcn_s_barrier();

  int buf = 0;
  for (int t = 0; t < 16; ++t){
    const int nstg = (buf >= 1) ? buf - 1 : 2;
    const ushort_t* SA = &S[buf * 24576];
    const ushort_t* SB = &S[buf * 24576 + 16384];
    short8 af[4], bfv[4];
#pragma unroll
    for (int mi = 0; mi < 4; ++mi) af[mi]  = *(const short8*)&SA[(arow + mi*16)*32 + slot];
#pragma unroll
    for (int nc = 0; nc < 4; ++nc) bfv[nc] = *(const short8*)&SB[(brow + nc*16)*32 + slot];
    if (t < 14){ STGA(0, t+2, nstg); STGB(0, t+2, nstg); }
    __builtin_amdgcn_s_barrier();
    __builtin_amdgcn_s_setprio(1);
#pragma unroll
    for (int mi = 0; mi < 4; ++mi)
#pragma unroll
      for (int nc = 0; nc < 4; ++nc)
        acc[mi][nc] = MFMA16(af[mi], bfv[nc], acc[mi][nc]);
    __builtin_amdgcn_s_setprio(0);
    __builtin_amdgcn_s_barrier();
#pragma unroll
    for (int mi = 0; mi < 4; ++mi) af[mi]  = *(const short8*)&SA[8192 + (arow + mi*16)*32 + slot];
#pragma unroll
    for (int nc = 0; nc < 4; ++nc) bfv[nc] = *(const short8*)&SB[4096 + (brow + nc*16)*32 + slot];
    if (t < 14){ STGA(1, t+2, nstg); STGB(1, t+2, nstg); }
    __builtin_amdgcn_s_barrier();
    __builtin_amdgcn_s_setprio(1);
#pragma unroll
    for (int mi = 0; mi < 4; ++mi)
#pragma unroll
      for (int nc = 0; nc < 4; ++nc)
        acc[mi][nc] = MFMA16(af[mi], bfv[nc], acc[mi][nc]);
    __builtin_amdgcn_s_setprio(0);
    if (t < 14)       asm volatile("s_waitcnt vmcnt(6)" ::: "memory");
    else if (t == 14) asm volatile("s_waitcnt vmcnt(0)" ::: "memory");
    __builtin_amdgcn_s_barrier();
    buf = (buf >= 2) ? 0 : buf + 1;
  }
#undef STGA
#undef STGB

  const int colBase = n0 + (wn << 6) + lr;
#pragma unroll
  for (int mi = 0; mi < 4; ++mi){
    const int row0 = m0 + (wm << 6) + mi*16 + lg*4;
#pragma unroll
    for (int nc = 0; nc < 4; ++nc){
      const int col = colBase + nc*16;
      const float bvv = bias[col];
#pragma unroll
      for (int i = 0; i < 4; ++i)
        Cout[(long)(row0 + i) * 1024 + col] = acc[mi][nc][i] + bvv;
    }
  }
}

// ---------------- flash attention (causal), 8-wave block, LDS-staged K/V ----------------
// (round-9 version: counted vmcnt(1), two raw s_barriers, 8 waves x 32 q-rows)
__global__ __launch_bounds__(512, 4) void attn(
    const ushort_t* __restrict__ Qb, const ushort_t* __restrict__ Kb,
    const ushort_t* __restrict__ Vt, ushort_t* __restrict__ yb){
  __shared__ __align__(16) ushort_t Ks[2][2048];
  __shared__ __align__(16) ushort_t Vs[2][2048];
  const int tid = threadIdx.x;
  const int w = tid >> 6, l = tid & 63;
  const int lq = l & 31;
  const int hi = l >> 5;
  const int xcd = blockIdx.x & 7;
  const int idx = blockIdx.x >> 3;          // 0..63
  const int hi5 = idx >> 5;                 // 0/1
  const int bh  = (xcd << 3) + ((idx >> 3) & 3) + hi5 * 4;
  const int qj  = hi5 ? (idx & 7) : 7 - (idx & 7);
  const int qc = (qj << 3) + w;
  const int q0 = qc << 5;
  const int ktmax = (qj << 3) + 7;
  const ushort_t* Qh = Qb + (long)bh * 2048 * 64;
  const ushort_t* Kh = Kb + (long)bh * 2048 * 64;
  const ushort_t* Vth = Vt + (long)bh * 64 * 2048;
  const int h8 = hi * 8;

  const ushort_t* qp = &Qh[(long)(q0 + lq) * 64 + h8];
  short8 qf0 = *(const short8*)(qp);
  short8 qf1 = *(const short8*)(qp + 16);
  short8 qf2 = *(const short8*)(qp + 32);
  short8 qf3 = *(const short8*)(qp + 48);

  const int stg_is_v = (w >= 4);
  long stg_src_off; int stg_dst_off;
  if (!stg_is_v){
    const int row = (w << 3) + (l >> 3);               // 0..31
    const int cl  = (l & 7) ^ (row & 7);
    stg_src_off = ((long)row << 6) + (cl << 3);
    stg_dst_off = (w << 9) + (l << 3);
  } else {
    const int row = ((w - 4) << 3) + (l >> 3);         // 0..31
    const int cl  = (l & 7) ^ (row & 7);
    const int dd  = row + ((cl & 4) << 3);
    stg_src_off = ((long)dd << 11) + ((cl & 3) << 3);
    stg_dst_off = ((w - 4) << 9) + (l << 3);
  }

  f32x16 o0 = {}, o1 = {};
  float lsum = 0.f;
  const float cl2 = 0.1803368801111204f;

  if (!stg_is_v) GL_LDS16(Kh + stg_src_off,  &Ks[0][stg_dst_off]);
  else           GL_LDS16(Vth + stg_src_off, &Vs[0][stg_dst_off]);
  asm volatile("s_waitcnt vmcnt(0)" ::: "memory");
  __builtin_amdgcn_s_barrier();

  int cur = 0;
  for (int kt = 0; kt <= ktmax; ++kt){
    if (kt < ktmax){
      const int k0n = (kt + 1) << 5;
      if (!stg_is_v) GL_LDS16(Kh + ((long)k0n << 6) + stg_src_off, &Ks[cur ^ 1][stg_dst_off]);
      else           GL_LDS16(Vth + k0n + stg_src_off,             &Vs[cur ^ 1][stg_dst_off]);
      asm volatile("s_waitcnt vmcnt(1)" ::: "memory");   // own stage(kt) done
    } else {
      asm volatile("s_waitcnt vmcnt(0)" ::: "memory");
    }
    __builtin_amdgcn_s_barrier();      // all waves' stage(kt) visible
    if (kt <= qc){
      const int swk = lq & 7;
      const ushort_t* kr = &Ks[cur][lq << 6];
      short8 kf0 = *(const short8*)&kr[((hi    ) ^ swk) << 3];
      short8 kf1 = *(const short8*)&kr[((2 + hi) ^ swk) << 3];
      short8 kf2 = *(const short8*)&kr[((4 + hi) ^ swk) << 3];
      short8 kf3 = *(const short8*)&kr[((6 + hi) ^ swk) << 3];
      const ushort_t* vr = &Vs[cur][lq << 6];
      short8 vf00 = *(const short8*)&vr[((hi    ) ^ swk) << 3];
      short8 vf01 = *(const short8*)&vr[((2 + hi) ^ swk) << 3];
      short8 vf10 = *(const short8*)&vr[((4 + hi) ^ swk) << 3];
      short8 vf11 = *(const short8*)&vr[((6 + hi) ^ swk) << 3];
      f32x16 s = {};
      s = MFMA32(kf0, qf0, s);
      s = MFMA32(kf1, qf1, s);
      s = MFMA32(kf2, qf2, s);
      s = MFMA32(kf3, qf3, s);
      if (kt == qc){
#pragma unroll
        for (int r = 0; r < 16; ++r){
          const int rk = (r & 3) + 8 * (r >> 2) + 4 * hi;
          if (rk > lq) s[r] = -1e30f;
        }
      }
#pragma unroll
      for (int r = 0; r < 16; ++r) s[r] = __builtin_amdgcn_exp2f(__builtin_fmaf(s[r], cl2, -2.0f));
      {
        float t0 = (s[0] + s[1]) + (s[2] + s[3]);
        float t1 = (s[4] + s[5]) + (s[6] + s[7]);
        float t2 = (s[8] + s[9]) + (s[10] + s[11]);
        float t3 = (s[12] + s[13]) + (s[14] + s[15]);
        lsum += (t0 + t1) + (t2 + t3);
      }
      uint32 a0 = cvtpk_bf16(s[0], s[1]),  b0 = cvtpk_bf16(s[4], s[5]);
      uint32 a1 = cvtpk_bf16(s[2], s[3]),  b1 = cvtpk_bf16(s[6], s[7]);
      uint32 a2 = cvtpk_bf16(s[8], s[9]),  b2 = cvtpk_bf16(s[12], s[13]);
      uint32 a3 = cvtpk_bf16(s[10], s[11]),b3 = cvtpk_bf16(s[14], s[15]);
      plswap(a0, b0);
      plswap(a1, b1);
      plswap(a2, b2);
      plswap(a3, b3);
      u32x4 pc0 = {a0, a1, b0, b1};
      u32x4 pc1 = {a2, a3, b2, b3};
      short8 pb0 = __builtin_bit_cast(short8, pc0);
      short8 pb1 = __builtin_bit_cast(short8, pc1);
      o0 = MFMA32(vf00, pb0, o0);
      o0 = MFMA32(vf01, pb1, o0);
      o1 = MFMA32(vf10, pb0, o1);
      o1 = MFMA32(vf11, pb1, o1);
    }
    __builtin_amdgcn_s_barrier();      // all waves done reading buf cur
    cur ^= 1;
  }
  lsum += __shfl_xor(lsum, 32);
  const float inv = 1.0f / lsum;
  const int b = bh >> 4, h = bh & 15;
  const int tok = q0 + lq;
  ushort_t* yrow = yb + (long)(b * 2048 + tok) * 1024 + h * 64;
#pragma unroll
  for (int g = 0; g < 4; ++g){
    short4v p0, p1;
#pragma unroll
    for (int j = 0; j < 4; ++j){
      p0[j] = (short)f2bf(o0[4*g + j] * inv);
      p1[j] = (short)f2bf(o1[4*g + j] * inv);
    }
    *(short4v*)&yrow[8*g + 4*hi]      = p0;
    *(short4v*)&yrow[32 + 8*g + 4*hi] = p1;
  }
}

// ---------------- launch ----------------
extern "C" void kernel_launch(void* const* d_in, const int* in_sizes, int n_in,
                              void* d_out, int out_size, void* d_ws, size_t ws_size,
                              hipStream_t stream){
  const float* x  = (const float*)d_in[0];
  const float* Wq = (const float*)d_in[1];
  const float* bq = (const float*)d_in[2];
  const float* Wk = (const float*)d_in[3];
  const float* bk = (const float*)d_in[4];
  const float* Wv = (const float*)d_in[5];
  const float* bv = (const float*)d_in[6];
  const float* Wo = (const float*)d_in[7];
  const float* bo = (const float*)d_in[8];
  char* ws = (char*)d_ws;
  ushort_t* xb   = (ushort_t*)(ws);                      // 16 MB; reused as yb after attn
  ushort_t* wqkv = (ushort_t*)(ws + 16777216);           // 6 MB (Q,K,V packed)
  ushort_t* wob  = (ushort_t*)(ws + 23068672);           // 2 MB
  float2*   tab  = (float2*)  (ws + 25165824);           // 512 KB
  ushort_t* Qb   = (ushort_t*)(ws + 25690112);           // 16 MB
  ushort_t* Kb   = (ushort_t*)(ws + 42467328);           // 16 MB
  ushort_t* Vt   = (ushort_t*)(ws + 59244544);           // 16 MB
  ushort_t* yb   = xb;

  convert_all<<<6400, 256, 0, stream>>>(x, Wq, Wk, Wv, Wo, xb, wqkv, wob, tab);
  gemm_qkv<<<768, 512, 0, stream>>>(xb, wqkv, bq, bk, bv, tab, Qb, Kb, Vt);
  attn<<<512, 512, 0, stream>>>(Qb, Kb, Vt, yb);
  gemm_out<<<256, 512, 0, stream>>>(yb, wob, bo, (float*)d_out);
}

// Round 12
// 156.007 us; speedup vs baseline: 1.0665x; 1.0151x over previous
//
#include <hip/hip_runtime.h>
#include <hip/hip_bf16.h>
#include <cstdint>

typedef __attribute__((ext_vector_type(8))) short short8;
typedef __attribute__((ext_vector_type(4))) short short4v;
typedef __attribute__((ext_vector_type(4))) float f32x4;
typedef __attribute__((ext_vector_type(16))) float f32x16;
typedef __attribute__((ext_vector_type(4))) unsigned int u32x4;
typedef unsigned short ushort_t;
typedef unsigned int uint32;

#define DEVI static __device__ __forceinline__

DEVI ushort_t f2bf(float f){
  uint32 u = __builtin_bit_cast(uint32, f);
  u += 0x7FFFu + ((u >> 16) & 1u);
  return (ushort_t)(u >> 16);
}
DEVI uint32 cvtpk_bf16(float lo, float hi){
  uint32 r;
  asm("v_cvt_pk_bf16_f32 %0, %1, %2" : "=v"(r) : "v"(lo), "v"(hi));
  return r;
}
DEVI void plswap(uint32& a, uint32& b){
  asm("v_permlane32_swap_b32 %0, %1" : "+v"(a), "+v"(b));
}

typedef __attribute__((address_space(1))) const uint32 g_u32;
typedef __attribute__((address_space(3))) uint32 l_u32;
#define GL_LDS16(gp, lp) __builtin_amdgcn_global_load_lds((g_u32*)(gp), (l_u32*)(lp), 16, 0, 0)

#define MFMA16(a, b, c) __builtin_amdgcn_mfma_f32_16x16x32_bf16(a, b, c, 0, 0, 0)
#define MFMA32(a, b, c) __builtin_amdgcn_mfma_f32_32x32x16_bf16(a, b, c, 0, 0, 0)

// ---------------- fp32 -> bf16 conversion + rope table ----------------
__global__ __launch_bounds__(256) void convert_all(
    const float* __restrict__ x, const float* __restrict__ wq, const float* __restrict__ wk,
    const float* __restrict__ wv, const float* __restrict__ wo,
    ushort_t* __restrict__ xb, ushort_t* __restrict__ wqkv, ushort_t* __restrict__ wob,
    float2* __restrict__ tab){
  int bid = blockIdx.x;
  if (bid >= 6144){
    const int idx = (bid - 6144) * 256 + threadIdx.x;    // 65536
    const int tok = idx >> 5, j = idx & 31;
    const float theta = exp2f(-(float)j * 0.4152410118609203f);   // log2(10000)/32
    const float ang = (float)(tok + 1) * theta;
    float s, c;
    sincosf(ang, &s, &c);
    tab[idx] = make_float2(c, s);
    return;
  }
  const float* src; ushort_t* dst; long base;
  if (bid < 4096){ src = x; dst = xb; base = (long)bid * 2048; }
  else {
    int r = bid - 4096; int sel = r >> 9; int o = r & 511;
    src = sel==0?wq: sel==1?wk: sel==2?wv: wo;
    dst = (sel<3) ? (wqkv + (long)sel * 1048576) : wob;
    base = (long)o * 2048;
  }
  long i = base + (long)threadIdx.x * 8;
  const float* p = src + i;
  float4 a = *(const float4*)p;
  float4 b = *(const float4*)(p + 4);
  short8 v;
  v[0]=(short)f2bf(a.x); v[1]=(short)f2bf(a.y); v[2]=(short)f2bf(a.z); v[3]=(short)f2bf(a.w);
  v[4]=(short)f2bf(b.x); v[5]=(short)f2bf(b.y); v[6]=(short)f2bf(b.z); v[7]=(short)f2bf(b.w);
  *(short8*)(dst + i) = v;
}

// ---------------- QKV GEMM, 256x128 tile, BK=64, tri-buffered 2-phase ----------------
__global__ __launch_bounds__(512, 2) void gemm_qkv(
    const ushort_t* __restrict__ A, const ushort_t* __restrict__ Bw,
    const float* __restrict__ bq, const float* __restrict__ bk, const float* __restrict__ bv,
    const float2* __restrict__ tab,
    ushort_t* __restrict__ Qb, ushort_t* __restrict__ Kb, ushort_t* __restrict__ Vt){
  __shared__ __align__(16) ushort_t S[73728];   // 144 KB
  const int tid = threadIdx.x;
  const int w = tid >> 6, l = tid & 63, lr = l & 15, lg = l >> 4;
  const int wm = w >> 1, wn = w & 1;            // 4M x 2N
  const int xcd = blockIdx.x & 7;
  const int l9  = blockIdx.x >> 3;              // 0..95
  const int bg  = l9 >> 5;                      // 0..2
  const int rem = l9 & 31;
  const int bm  = ((xcd & 3) << 3) + (rem >> 2);
  const int bn  = ((xcd >> 2) * 12) + (bg << 2) + (rem & 3);
  const int m0 = bm << 8, n0 = bn << 7;
  const int rbase = tid >> 2;
  const int swzk = (tid & 3) ^ ((tid >> 3) & 3);
  const ushort_t* aS = A  + (long)(m0 + rbase) * 1024 + swzk * 8;
  const ushort_t* bS = Bw + (long)(n0 + rbase) * 1024 + swzk * 8;
  const int slot = (lg ^ ((lr >> 1) & 3)) << 3;
  const int arow = wm * 64 + lr;
  const int brow = wn * 64 + lr;
  f32x4 acc[4][4] = {};

#define STGA(kk, t, bf_) do{ \
    const ushort_t* _s = aS + (long)(t)*64 + (kk)*32; \
    ushort_t* _d = &S[(bf_)*24576 + (kk)*8192 + tid*8]; \
    GL_LDS16(_s,          _d); \
    GL_LDS16(_s + 131072, _d + 4096); }while(0)
#define STGB(kk, t, bf_) do{ \
    GL_LDS16(bS + (long)(t)*64 + (kk)*32, \
             &S[(bf_)*24576 + 16384 + (kk)*4096 + tid*8]); }while(0)

  STGA(0,0,0); STGB(0,0,0); STGA(1,0,0); STGB(1,0,0);
  STGA(0,1,1); STGB(0,1,1); STGA(1,1,1); STGB(1,1,1);
  asm volatile("s_waitcnt vmcnt(6)" ::: "memory");
  __builtin_amdgcn_s_barrier();

  int buf = 0;
  for (int t = 0; t < 16; ++t){
    const int nstg = (buf >= 1) ? buf - 1 : 2;
    const ushort_t* SA = &S[buf * 24576];
    const ushort_t* SB = &S[buf * 24576 + 16384];
    short8 af[4], bfv[4];
#pragma unroll
    for (int mi = 0; mi < 4; ++mi) af[mi]  = *(const short8*)&SA[(arow + mi*16)*32 + slot];
#pragma unroll
    for (int nc = 0; nc < 4; ++nc) bfv[nc] = *(const short8*)&SB[(brow + nc*16)*32 + slot];
    if (t < 14){ STGA(0, t+2, nstg); STGB(0, t+2, nstg); }
    __builtin_amdgcn_s_barrier();
    __builtin_amdgcn_s_setprio(1);
#pragma unroll
    for (int mi = 0; mi < 4; ++mi)
#pragma unroll
      for (int nc = 0; nc < 4; ++nc)
        acc[mi][nc] = MFMA16(af[mi], bfv[nc], acc[mi][nc]);
    __builtin_amdgcn_s_setprio(0);
    __builtin_amdgcn_s_barrier();
#pragma unroll
    for (int mi = 0; mi < 4; ++mi) af[mi]  = *(const short8*)&SA[8192 + (arow + mi*16)*32 + slot];
#pragma unroll
    for (int nc = 0; nc < 4; ++nc) bfv[nc] = *(const short8*)&SB[4096 + (brow + nc*16)*32 + slot];
    if (t < 14){ STGA(1, t+2, nstg); STGB(1, t+2, nstg); }
    __builtin_amdgcn_s_barrier();
    __builtin_amdgcn_s_setprio(1);
#pragma unroll
    for (int mi = 0; mi < 4; ++mi)
#pragma unroll
      for (int nc = 0; nc < 4; ++nc)
        acc[mi][nc] = MFMA16(af[mi], bfv[nc], acc[mi][nc]);
    __builtin_amdgcn_s_setprio(0);
    if (t < 14)       asm volatile("s_waitcnt vmcnt(6)" ::: "memory");
    else if (t == 14) asm volatile("s_waitcnt vmcnt(0)" ::: "memory");
    __builtin_amdgcn_s_barrier();
    buf = (buf >= 2) ? 0 : buf + 1;
  }
#undef STGA
#undef STGB

  const int colX = n0 + (wn << 6);
  const int sel = colX >> 10;                // 0=Q 1=K 2=V
  const int h = (colX >> 6) & 15;
  const int cB = (colX & 1023) + lr;
  if (sel < 2){
    ushort_t* dst = sel ? Kb : Qb;
    const float* bp = sel ? bk : bq;
    const float bvs[4] = {bp[cB], bp[cB+16], bp[cB+32], bp[cB+48]};
#pragma unroll
    for (int mi = 0; mi < 4; ++mi){
      const int row0 = m0 + (wm << 6) + mi*16 + lg*4;
#pragma unroll
      for (int i = 0; i < 4; ++i){
        const int r = row0 + i;
        const int b = r >> 11, tok = r & 2047;
#pragma unroll
        for (int nc = 0; nc < 2; ++nc){
          const int j = nc*16 + lr;
          const float2 cs = tab[tok*32 + j];
          const float v0 = acc[mi][nc][i]   + bvs[nc];
          const float v1 = acc[mi][nc+2][i] + bvs[nc+2];
          const long base = (((long)((b<<4) + h) * 2048 + tok) << 6) + j;
          dst[base]      = f2bf(v0 * cs.x - v1 * cs.y);
          dst[base + 32] = f2bf(v1 * cs.x + v0 * cs.y);
        }
      }
    }
  } else {
    // V: LDS transpose -> coalesced Vt writes
    const float bvs[4] = {bv[cB], bv[cB+16], bv[cB+32], bv[cB+48]};
    ushort_t* T = &S[w * 4608];          // wave-private [64 d][72] bf16
#pragma unroll
    for (int nc = 0; nc < 4; ++nc){
      const int d = nc*16 + lr;
      const int dx = d & 7;
#pragma unroll
      for (int mi = 0; mi < 4; ++mi){
        const int col = mi*16 + lg*4;
        const int scol = (((col >> 3) ^ dx) << 3) + (col & 7);
        const uint32 p0 = cvtpk_bf16(acc[mi][nc][0] + bvs[nc], acc[mi][nc][1] + bvs[nc]);
        const uint32 p1 = cvtpk_bf16(acc[mi][nc][2] + bvs[nc], acc[mi][nc][3] + bvs[nc]);
        uint32* dp = (uint32*)&T[d*72 + scol];
        dp[0] = p0; dp[1] = p1;
      }
    }
    const int rowbase = m0 + (wm << 6);
    const int b = rowbase >> 11;
    const int tok0 = rowbase & 2047;
    ushort_t* vbase = Vt + (((long)((b << 4) + h)) << 17);   // *64*2048
    const int dl = l >> 3, c8 = l & 7;
#pragma unroll
    for (int it = 0; it < 8; ++it){
      const int d = dl + it*8;
      short8 v = *(const short8*)&T[d*72 + ((c8 ^ (d & 7)) << 3)];
      *(short8*)&vbase[((long)d << 11) + tok0 + (c8 << 3)] = v;
    }
  }
}

// ---------------- output GEMM, 256x128, BK=64, tri-buffered (fp32 out) ----------------
__global__ __launch_bounds__(512, 2) void gemm_out(
    const ushort_t* __restrict__ A, const ushort_t* __restrict__ Bw,
    const float* __restrict__ bias, float* __restrict__ Cout){
  __shared__ __align__(16) ushort_t S[73728];   // 144 KB
  const int tid = threadIdx.x;
  const int w = tid >> 6, l = tid & 63, lr = l & 15, lg = l >> 4;
  const int wm = w >> 1, wn = w & 1;
  const int xcd = blockIdx.x & 7;
  const int l9  = blockIdx.x >> 3;              // 0..31
  const int bm  = (xcd << 2) + (l9 >> 3);
  const int bn  = l9 & 7;
  const int m0 = bm << 8, n0 = bn << 7;
  const int rbase = tid >> 2;
  const int swzk = (tid & 3) ^ ((tid >> 3) & 3);
  const ushort_t* aS = A  + (long)(m0 + rbase) * 1024 + swzk * 8;
  const ushort_t* bS = Bw + (long)(n0 + rbase) * 1024 + swzk * 8;
  const int slot = (lg ^ ((lr >> 1) & 3)) << 3;
  const int arow = wm * 64 + lr;
  const int brow = wn * 64 + lr;
  f32x4 acc[4][4] = {};

#define STGA(kk, t, bf_) do{ \
    const ushort_t* _s = aS + (long)(t)*64 + (kk)*32; \
    ushort_t* _d = &S[(bf_)*24576 + (kk)*8192 + tid*8]; \
    GL_LDS16(_s,          _d); \
    GL_LDS16(_s + 131072, _d + 4096); }while(0)
#define STGB(kk, t, bf_) do{ \
    GL_LDS16(bS + (long)(t)*64 + (kk)*32, \
             &S[(bf_)*24576 + 16384 + (kk)*4096 + tid*8]); }while(0)

  STGA(0,0,0); STGB(0,0,0); STGA(1,0,0); STGB(1,0,0);
  STGA(0,1,1); STGB(0,1,1); STGA(1,1,1); STGB(1,1,1);
  asm volatile("s_waitcnt vmcnt(6)" ::: "memory");
  __builtin_amdgcn_s_barrier();

  int buf = 0;
  for (int t = 0; t < 16; ++t){
    const int nstg = (buf >= 1) ? buf - 1 : 2;
    const ushort_t* SA = &S[buf * 24576];
    const ushort_t* SB = &S[buf * 24576 + 16384];
    short8 af[4], bfv[4];
#pragma unroll
    for (int mi = 0; mi < 4; ++mi) af[mi]  = *(const short8*)&SA[(arow + mi*16)*32 + slot];
#pragma unroll
    for (int nc = 0; nc < 4; ++nc) bfv[nc] = *(const short8*)&SB[(brow + nc*16)*32 + slot];
    if (t < 14){ STGA(0, t+2, nstg); STGB(0, t+2, nstg); }
    __builtin_amdgcn_s_barrier();
    __builtin_amdgcn_s_setprio(1);
#pragma unroll
    for (int mi = 0; mi < 4; ++mi)
#pragma unroll
      for (int nc = 0; nc < 4; ++nc)
        acc[mi][nc] = MFMA16(af[mi], bfv[nc], acc[mi][nc]);
    __builtin_amdgcn_s_setprio(0);
    __builtin_amdgcn_s_barrier();
#pragma unroll
    for (int mi = 0; mi < 4; ++mi) af[mi]  = *(const short8*)&SA[8192 + (arow + mi*16)*32 + slot];
#pragma unroll
    for (int nc = 0; nc < 4; ++nc) bfv[nc] = *(const short8*)&SB[4096 + (brow + nc*16)*32 + slot];
    if (t < 14){ STGA(1, t+2, nstg); STGB(1, t+2, nstg); }
    __builtin_amdgcn_s_barrier();
    __builtin_amdgcn_s_setprio(1);
#pragma unroll
    for (int mi = 0; mi < 4; ++mi)
#pragma unroll
      for (int nc = 0; nc < 4; ++nc)
        acc[mi][nc] = MFMA16(af[mi], bfv[nc], acc[mi][nc]);
    __builtin_amdgcn_s_setprio(0);
    if (t < 14)       asm volatile("s_waitcnt vmcnt(6)" ::: "memory");
    else if (t == 14) asm volatile("s_waitcnt vmcnt(0)" ::: "memory");
    __builtin_amdgcn_s_barrier();
    buf = (buf >= 2) ? 0 : buf + 1;
  }
#undef STGA
#undef STGB

  const int colBase = n0 + (wn << 6) + lr;
#pragma unroll
  for (int mi = 0; mi < 4; ++mi){
    const int row0 = m0 + (wm << 6) + mi*16 + lg*4;
#pragma unroll
    for (int nc = 0; nc < 4; ++nc){
      const int col = colBase + nc*16;
      const float bvv = bias[col];
#pragma unroll
      for (int i = 0; i < 4; ++i)
        Cout[(long)(row0 + i) * 1024 + col] = acc[mi][nc][i] + bvv;
    }
  }
}

// ---------------- flash attention (causal), 8-wave block, KBLK=64 ----------------
// Wave w owns q-chunk qc = 8*qj + w (32 rows). K/V staged in 64-key tiles,
// double-buffered (32 KB), 2 loads/thread/tile, counted vmcnt(2).
// Diagonal 64-tile: parity ksub gets triangular mask; fully-masked ksub skipped.
__global__ __launch_bounds__(512, 4) void attn(
    const ushort_t* __restrict__ Qb, const ushort_t* __restrict__ Kb,
    const ushort_t* __restrict__ Vt, ushort_t* __restrict__ yb){
  __shared__ __align__(16) ushort_t Ks[2][4096];   // [64 key][64 d]
  __shared__ __align__(16) ushort_t Vs[2][4096];   // [64 d][64 k]
  const int tid = threadIdx.x;
  const int w = tid >> 6, l = tid & 63;
  const int lq = l & 31;
  const int hi = l >> 5;
  const int xcd = blockIdx.x & 7;
  const int idx = blockIdx.x >> 3;          // 0..63
  const int hi5 = idx >> 5;                 // 0/1
  const int bh  = (xcd << 3) + ((idx >> 3) & 3) + hi5 * 4;
  const int qj  = hi5 ? (idx & 7) : 7 - (idx & 7);
  const int qc = (qj << 3) + w;
  const int q0 = qc << 5;
  const int wkt = qc >> 1;                  // wave's diagonal 64-key tile
  const int p   = qc & 1;                   // which ksub holds the diagonal
  const int ktmax = (qj << 2) + 3;          // block's last 64-key tile
  const ushort_t* Qh = Qb + (long)bh * 131072;
  const ushort_t* Kh = Kb + (long)bh * 131072;
  const ushort_t* Vth = Vt + (long)bh * 131072;
  const int h8 = hi * 8;

  const ushort_t* qp = &Qh[(long)(q0 + lq) * 64 + h8];
  short8 qf0 = *(const short8*)(qp);
  short8 qf1 = *(const short8*)(qp + 16);
  short8 qf2 = *(const short8*)(qp + 32);
  short8 qf3 = *(const short8*)(qp + 48);

  // staging: waves 0-3 -> K (8KB), waves 4-7 -> V (8KB); 2 loads/thread.
  const int stg_is_v = (w >= 4);
  const int wg = stg_is_v ? (w - 4) : w;            // 0..3
  const int row0 = (wg << 3) + (l >> 3);            // 0..31
  const int c8 = (l & 7);
  const int cc = c8 ^ (row0 & 7);                   // same for row0+32
  long src0, src1;
  if (!stg_is_v){
    src0 = ((long)row0 << 6) + (cc << 3);           // + k0*64 at use
    src1 = ((long)(row0 + 32) << 6) + (cc << 3);
  } else {
    src0 = ((long)row0 << 11) + (cc << 3);          // + k0 at use
    src1 = ((long)(row0 + 32) << 11) + (cc << 3);
  }
  const int dst0 = (wg << 9) + (l << 3);
  const int dst1 = 2048 + dst0;

  f32x16 o0 = {}, o1 = {};
  float lsum = 0.f;
  const float cl2 = 0.1803368801111204f;   // log2(e)/8

  if (!stg_is_v){ GL_LDS16(Kh + src0,  &Ks[0][dst0]); GL_LDS16(Kh + src1,  &Ks[0][dst1]); }
  else          { GL_LDS16(Vth + src0, &Vs[0][dst0]); GL_LDS16(Vth + src1, &Vs[0][dst1]); }

  int cur = 0;
  for (int kt = 0; kt <= ktmax; ++kt){
    if (kt < ktmax){
      const long k0n = (long)(kt + 1) << 6;
      if (!stg_is_v){
        GL_LDS16(Kh + (k0n << 6) + src0, &Ks[cur ^ 1][dst0]);
        GL_LDS16(Kh + (k0n << 6) + src1, &Ks[cur ^ 1][dst1]);
      } else {
        GL_LDS16(Vth + k0n + src0, &Vs[cur ^ 1][dst0]);
        GL_LDS16(Vth + k0n + src1, &Vs[cur ^ 1][dst1]);
      }
      asm volatile("s_waitcnt vmcnt(2)" ::: "memory");   // own stage(kt) done
    } else {
      asm volatile("s_waitcnt vmcnt(0)" ::: "memory");
    }
    __builtin_amdgcn_s_barrier();      // all waves' stage(kt) visible
    if (kt <= wkt){
      const bool diag = (kt == wkt);
      const int swl = lq & 7;
#pragma unroll
      for (int ksub = 0; ksub < 2; ++ksub){
        if (diag && ksub > p) continue;          // fully-masked half: skip
        const ushort_t* kr = &Ks[cur][(ksub * 32 + lq) << 6];
        short8 kf0 = *(const short8*)&kr[((    hi) ^ swl) << 3];
        short8 kf1 = *(const short8*)&kr[((2 + hi) ^ swl) << 3];
        short8 kf2 = *(const short8*)&kr[((4 + hi) ^ swl) << 3];
        short8 kf3 = *(const short8*)&kr[((6 + hi) ^ swl) << 3];
        f32x16 s = {};
        s = MFMA32(kf0, qf0, s);
        s = MFMA32(kf1, qf1, s);
        s = MFMA32(kf2, qf2, s);
        s = MFMA32(kf3, qf3, s);
        if (diag && ksub == p){
#pragma unroll
          for (int r = 0; r < 16; ++r){
            const int rk = (r & 3) + 8 * (r >> 2) + 4 * hi;
            if (rk > lq) s[r] = -1e30f;
          }
        }
#pragma unroll
        for (int r = 0; r < 16; ++r) s[r] = __builtin_amdgcn_exp2f(__builtin_fmaf(s[r], cl2, -2.0f));
        {
          float t0 = (s[0] + s[1]) + (s[2] + s[3]);
          float t1 = (s[4] + s[5]) + (s[6] + s[7]);
          float t2 = (s[8] + s[9]) + (s[10] + s[11]);
          float t3 = (s[12] + s[13]) + (s[14] + s[15]);
          lsum += (t0 + t1) + (t2 + t3);
        }
        uint32 a0 = cvtpk_bf16(s[0], s[1]),  b0 = cvtpk_bf16(s[4], s[5]);
        uint32 a1 = cvtpk_bf16(s[2], s[3]),  b1 = cvtpk_bf16(s[6], s[7]);
        uint32 a2 = cvtpk_bf16(s[8], s[9]),  b2 = cvtpk_bf16(s[12], s[13]);
        uint32 a3 = cvtpk_bf16(s[10], s[11]),b3 = cvtpk_bf16(s[14], s[15]);
        plswap(a0, b0);
        plswap(a1, b1);
        plswap(a2, b2);
        plswap(a3, b3);
        u32x4 pc0 = {a0, a1, b0, b1};
        u32x4 pc1 = {a2, a3, b2, b3};
        short8 pb0 = __builtin_bit_cast(short8, pc0);
        short8 pb1 = __builtin_bit_cast(short8, pc1);
        // V fragments: rows d=lq / lq+32; k-chunks (ksub*4 + {0,2} + hi) ^ swl
        const ushort_t* vrlo = &Vs[cur][lq << 6];
        const ushort_t* vrhi = &Vs[cur][(lq + 32) << 6];
        const int cbase = ksub << 2;
        short8 vf00 = *(const short8*)&vrlo[((cbase +     hi) ^ swl) << 3];
        short8 vf01 = *(const short8*)&vrlo[((cbase + 2 + hi) ^ swl) << 3];
        short8 vf10 = *(const short8*)&vrhi[((cbase +     hi) ^ swl) << 3];
        short8 vf11 = *(const short8*)&vrhi[((cbase + 2 + hi) ^ swl) << 3];
        o0 = MFMA32(vf00, pb0, o0);
        o0 = MFMA32(vf01, pb1, o0);
        o1 = MFMA32(vf10, pb0, o1);
        o1 = MFMA32(vf11, pb1, o1);
      }
    }
    __builtin_amdgcn_s_barrier();      // all waves done reading buf cur
    cur ^= 1;
  }
  lsum += __shfl_xor(lsum, 32);
  const float inv = 1.0f / lsum;
  const int b = bh >> 4, h = bh & 15;
  const int tok = q0 + lq;
  ushort_t* yrow = yb + (long)(b * 2048 + tok) * 1024 + h * 64;
#pragma unroll
  for (int g = 0; g < 4; ++g){
    short4v p0, p1;
#pragma unroll
    for (int j = 0; j < 4; ++j){
      p0[j] = (short)f2bf(o0[4*g + j] * inv);
      p1[j] = (short)f2bf(o1[4*g + j] * inv);
    }
    *(short4v*)&yrow[8*g + 4*hi]      = p0;
    *(short4v*)&yrow[32 + 8*g + 4*hi] = p1;
  }
}

// ---------------- launch ----------------
extern "C" void kernel_launch(void* const* d_in, const int* in_sizes, int n_in,
                              void* d_out, int out_size, void* d_ws, size_t ws_size,
                              hipStream_t stream){
  const float* x  = (const float*)d_in[0];
  const float* Wq = (const float*)d_in[1];
  const float* bq = (const float*)d_in[2];
  const float* Wk = (const float*)d_in[3];
  const float* bk = (const float*)d_in[4];
  const float* Wv = (const float*)d_in[5];
  const float* bv = (const float*)d_in[6];
  const float* Wo = (const float*)d_in[7];
  const float* bo = (const float*)d_in[8];
  char* ws = (char*)d_ws;
  ushort_t* xb   = (ushort_t*)(ws);                      // 16 MB; reused as yb after attn
  ushort_t* wqkv = (ushort_t*)(ws + 16777216);           // 6 MB (Q,K,V packed)
  ushort_t* wob  = (ushort_t*)(ws + 23068672);           // 2 MB
  float2*   tab  = (float2*)  (ws + 25165824);           // 512 KB
  ushort_t* Qb   = (ushort_t*)(ws + 25690112);           // 16 MB
  ushort_t* Kb   = (ushort_t*)(ws + 42467328);           // 16 MB
  ushort_t* Vt   = (ushort_t*)(ws + 59244544);           // 16 MB
  ushort_t* yb   = xb;

  convert_all<<<6400, 256, 0, stream>>>(x, Wq, Wk, Wv, Wo, xb, wqkv, wob, tab);
  gemm_qkv<<<768, 512, 0, stream>>>(xb, wqkv, bq, bk, bv, tab, Qb, Kb, Vt);
  attn<<<512, 512, 0, stream>>>(Qb, Kb, Vt, yb);
  gemm_out<<<256, 512, 0, stream>>>(yb, wob, bo, (float*)d_out);
}

// Round 13
// 149.994 us; speedup vs baseline: 1.1092x; 1.0401x over previous
//
#include <hip/hip_runtime.h>
#include <hip/hip_bf16.h>
#include <cstdint>

typedef __attribute__((ext_vector_type(8))) short short8;
typedef __attribute__((ext_vector_type(4))) short short4v;
typedef __attribute__((ext_vector_type(4))) float f32x4;
typedef __attribute__((ext_vector_type(16))) float f32x16;
typedef __attribute__((ext_vector_type(4))) unsigned int u32x4;
typedef unsigned short ushort_t;
typedef unsigned int uint32;

#define DEVI static __device__ __forceinline__

DEVI ushort_t f2bf(float f){
  uint32 u = __builtin_bit_cast(uint32, f);
  u += 0x7FFFu + ((u >> 16) & 1u);
  return (ushort_t)(u >> 16);
}
DEVI uint32 cvtpk_bf16(float lo, float hi){
  uint32 r;
  asm("v_cvt_pk_bf16_f32 %0, %1, %2" : "=v"(r) : "v"(lo), "v"(hi));
  return r;
}
DEVI void plswap(uint32& a, uint32& b){
  asm("v_permlane32_swap_b32 %0, %1" : "+v"(a), "+v"(b));
}

typedef __attribute__((address_space(1))) const uint32 g_u32;
typedef __attribute__((address_space(3))) uint32 l_u32;
#define GL_LDS16(gp, lp) __builtin_amdgcn_global_load_lds((g_u32*)(gp), (l_u32*)(lp), 16, 0, 0)

#define MFMA16(a, b, c) __builtin_amdgcn_mfma_f32_16x16x32_bf16(a, b, c, 0, 0, 0)
#define MFMA32(a, b, c) __builtin_amdgcn_mfma_f32_32x32x16_bf16(a, b, c, 0, 0, 0)

// ---------------- fp32 -> bf16 conversion + rope table ----------------
__global__ __launch_bounds__(256) void convert_all(
    const float* __restrict__ x, const float* __restrict__ wq, const float* __restrict__ wk,
    const float* __restrict__ wv, const float* __restrict__ wo,
    ushort_t* __restrict__ xb, ushort_t* __restrict__ wqkv, ushort_t* __restrict__ wob,
    float2* __restrict__ tab){
  int bid = blockIdx.x;
  if (bid >= 6144){
    const int idx = (bid - 6144) * 256 + threadIdx.x;    // 65536
    const int tok = idx >> 5, j = idx & 31;
    const float theta = exp2f(-(float)j * 0.4152410118609203f);   // log2(10000)/32
    const float ang = (float)(tok + 1) * theta;
    float s, c;
    sincosf(ang, &s, &c);
    tab[idx] = make_float2(c, s);
    return;
  }
  const float* src; ushort_t* dst; long base;
  if (bid < 4096){ src = x; dst = xb; base = (long)bid * 2048; }
  else {
    int r = bid - 4096; int sel = r >> 9; int o = r & 511;
    src = sel==0?wq: sel==1?wk: sel==2?wv: wo;
    dst = (sel<3) ? (wqkv + (long)sel * 1048576) : wob;
    base = (long)o * 2048;
  }
  long i = base + (long)threadIdx.x * 8;
  const float* p = src + i;
  float4 a = *(const float4*)p;
  float4 b = *(const float4*)(p + 4);
  short8 v;
  v[0]=(short)f2bf(a.x); v[1]=(short)f2bf(a.y); v[2]=(short)f2bf(a.z); v[3]=(short)f2bf(a.w);
  v[4]=(short)f2bf(b.x); v[5]=(short)f2bf(b.y); v[6]=(short)f2bf(b.z); v[7]=(short)f2bf(b.w);
  *(short8*)(dst + i) = v;
}

// ---------------- QKV GEMM, 256x128 tile, BK=32, tri-buffered, 1 barrier/tile ----------------
// LDS 72 KB -> 2 blocks/CU (4 waves/SIMD). 3 loads/thread/tile staged 2 tiles
// ahead; ONE vmcnt(3) + ONE s_barrier per tile. Same swizzle family as before.
__global__ __launch_bounds__(512, 2) void gemm_qkv(
    const ushort_t* __restrict__ A, const ushort_t* __restrict__ Bw,
    const float* __restrict__ bq, const float* __restrict__ bk, const float* __restrict__ bv,
    const float2* __restrict__ tab,
    ushort_t* __restrict__ Qb, ushort_t* __restrict__ Kb, ushort_t* __restrict__ Vt){
  __shared__ __align__(16) ushort_t S[36864];   // 72 KB: 3 bufs x (A 16KB | B 8KB)
  const int tid = threadIdx.x;
  const int w = tid >> 6, l = tid & 63, lr = l & 15, lg = l >> 4;
  const int wm = w >> 1, wn = w & 1;            // 4M x 2N
  const int xcd = blockIdx.x & 7;
  const int l9  = blockIdx.x >> 3;              // 0..95
  const int bg  = l9 >> 5;                      // 0..2
  const int rem = l9 & 31;
  const int bm  = ((xcd & 3) << 3) + (rem >> 2);
  const int bn  = ((xcd >> 2) * 12) + (bg << 2) + (rem & 3);
  const int m0 = bm << 8, n0 = bn << 7;
  const int rbase = tid >> 2;
  const int swzk = (tid & 3) ^ ((tid >> 3) & 3);
  const ushort_t* aS = A  + (long)(m0 + rbase) * 1024 + swzk * 8;
  const ushort_t* bS = Bw + (long)(n0 + rbase) * 1024 + swzk * 8;
  const int slot = (lg ^ ((lr >> 1) & 3)) << 3;
  const int arow = wm * 64 + lr;
  const int brow = wn * 64 + lr;
  f32x4 acc[4][4] = {};

#define STGA(t, bf_) do{ \
    const ushort_t* _s = aS + (long)(t)*32; \
    ushort_t* _d = &S[(bf_)*12288 + tid*8]; \
    GL_LDS16(_s,          _d); \
    GL_LDS16(_s + 131072, _d + 4096); }while(0)
#define STGB(t, bf_) do{ \
    GL_LDS16(bS + (long)(t)*32, &S[(bf_)*12288 + 8192 + tid*8]); }while(0)

  // prologue: tiles 0,1 issued; tile 0 resident
  STGA(0,0); STGB(0,0);
  STGA(1,1); STGB(1,1);
  asm volatile("s_waitcnt vmcnt(3)" ::: "memory");
  __builtin_amdgcn_s_barrier();

  int buf = 0;
  for (int t = 0; t < 32; ++t){
    const int nstg = (buf >= 1) ? buf - 1 : 2;     // (t+2)%3
    const ushort_t* SA = &S[buf * 12288];
    const ushort_t* SB = &S[buf * 12288 + 8192];
    short8 af[4], bfv[4];
#pragma unroll
    for (int mi = 0; mi < 4; ++mi) af[mi]  = *(const short8*)&SA[(arow + mi*16)*32 + slot];
#pragma unroll
    for (int nc = 0; nc < 4; ++nc) bfv[nc] = *(const short8*)&SB[(brow + nc*16)*32 + slot];
    if (t < 30){ STGA(t+2, nstg); STGB(t+2, nstg); }
    __builtin_amdgcn_s_setprio(1);
#pragma unroll
    for (int mi = 0; mi < 4; ++mi)
#pragma unroll
      for (int nc = 0; nc < 4; ++nc)
        acc[mi][nc] = MFMA16(af[mi], bfv[nc], acc[mi][nc]);
    __builtin_amdgcn_s_setprio(0);
    if (t < 30)       asm volatile("s_waitcnt vmcnt(3)" ::: "memory");  // tile t+1 resident
    else if (t == 30) asm volatile("s_waitcnt vmcnt(0)" ::: "memory");
    __builtin_amdgcn_s_barrier();
    buf = (buf >= 2) ? 0 : buf + 1;
  }
#undef STGA
#undef STGB

  const int colX = n0 + (wn << 6);
  const int sel = colX >> 10;                // 0=Q 1=K 2=V
  const int h = (colX >> 6) & 15;
  const int cB = (colX & 1023) + lr;
  if (sel < 2){
    ushort_t* dst = sel ? Kb : Qb;
    const float* bp = sel ? bk : bq;
    const float bvs[4] = {bp[cB], bp[cB+16], bp[cB+32], bp[cB+48]};
#pragma unroll
    for (int mi = 0; mi < 4; ++mi){
      const int row0 = m0 + (wm << 6) + mi*16 + lg*4;
#pragma unroll
      for (int i = 0; i < 4; ++i){
        const int r = row0 + i;
        const int b = r >> 11, tok = r & 2047;
#pragma unroll
        for (int nc = 0; nc < 2; ++nc){
          const int j = nc*16 + lr;
          const float2 cs = tab[tok*32 + j];
          const float v0 = acc[mi][nc][i]   + bvs[nc];
          const float v1 = acc[mi][nc+2][i] + bvs[nc+2];
          const long base = (((long)((b<<4) + h) * 2048 + tok) << 6) + j;
          dst[base]      = f2bf(v0 * cs.x - v1 * cs.y);
          dst[base + 32] = f2bf(v1 * cs.x + v0 * cs.y);
        }
      }
    }
  } else {
    // V: LDS transpose -> coalesced Vt writes (wave-private 4608-ushort region)
    const float bvs[4] = {bv[cB], bv[cB+16], bv[cB+32], bv[cB+48]};
    ushort_t* T = &S[w * 4608];          // 8 waves x 4608 = 36864 ushorts, exact fit
#pragma unroll
    for (int nc = 0; nc < 4; ++nc){
      const int d = nc*16 + lr;
      const int dx = d & 7;
#pragma unroll
      for (int mi = 0; mi < 4; ++mi){
        const int col = mi*16 + lg*4;
        const int scol = (((col >> 3) ^ dx) << 3) + (col & 7);
        const uint32 p0 = cvtpk_bf16(acc[mi][nc][0] + bvs[nc], acc[mi][nc][1] + bvs[nc]);
        const uint32 p1 = cvtpk_bf16(acc[mi][nc][2] + bvs[nc], acc[mi][nc][3] + bvs[nc]);
        uint32* dp = (uint32*)&T[d*72 + scol];
        dp[0] = p0; dp[1] = p1;
      }
    }
    const int rowbase = m0 + (wm << 6);
    const int b = rowbase >> 11;
    const int tok0 = rowbase & 2047;
    ushort_t* vbase = Vt + (((long)((b << 4) + h)) << 17);   // *64*2048
    const int dl = l >> 3, c8 = l & 7;
#pragma unroll
    for (int it = 0; it < 8; ++it){
      const int d = dl + it*8;
      short8 v = *(const short8*)&T[d*72 + ((c8 ^ (d & 7)) << 3)];
      *(short8*)&vbase[((long)d << 11) + tok0 + (c8 << 3)] = v;
    }
  }
}

// ---------------- output GEMM, 256x128, BK=32, tri-buffered, 1 barrier/tile ----------------
__global__ __launch_bounds__(512, 2) void gemm_out(
    const ushort_t* __restrict__ A, const ushort_t* __restrict__ Bw,
    const float* __restrict__ bias, float* __restrict__ Cout){
  __shared__ __align__(16) ushort_t S[36864];   // 72 KB
  const int tid = threadIdx.x;
  const int w = tid >> 6, l = tid & 63, lr = l & 15, lg = l >> 4;
  const int wm = w >> 1, wn = w & 1;
  const int xcd = blockIdx.x & 7;
  const int l9  = blockIdx.x >> 3;              // 0..31
  const int bm  = (xcd << 2) + (l9 >> 3);
  const int bn  = l9 & 7;
  const int m0 = bm << 8, n0 = bn << 7;
  const int rbase = tid >> 2;
  const int swzk = (tid & 3) ^ ((tid >> 3) & 3);
  const ushort_t* aS = A  + (long)(m0 + rbase) * 1024 + swzk * 8;
  const ushort_t* bS = Bw + (long)(n0 + rbase) * 1024 + swzk * 8;
  const int slot = (lg ^ ((lr >> 1) & 3)) << 3;
  const int arow = wm * 64 + lr;
  const int brow = wn * 64 + lr;
  f32x4 acc[4][4] = {};

#define STGA(t, bf_) do{ \
    const ushort_t* _s = aS + (long)(t)*32; \
    ushort_t* _d = &S[(bf_)*12288 + tid*8]; \
    GL_LDS16(_s,          _d); \
    GL_LDS16(_s + 131072, _d + 4096); }while(0)
#define STGB(t, bf_) do{ \
    GL_LDS16(bS + (long)(t)*32, &S[(bf_)*12288 + 8192 + tid*8]); }while(0)

  STGA(0,0); STGB(0,0);
  STGA(1,1); STGB(1,1);
  asm volatile("s_waitcnt vmcnt(3)" ::: "memory");
  __builtin_amdgcn_s_barrier();

  int buf = 0;
  for (int t = 0; t < 32; ++t){
    const int nstg = (buf >= 1) ? buf - 1 : 2;
    const ushort_t* SA = &S[buf * 12288];
    const ushort_t* SB = &S[buf * 12288 + 8192];
    short8 af[4], bfv[4];
#pragma unroll
    for (int mi = 0; mi < 4; ++mi) af[mi]  = *(const short8*)&SA[(arow + mi*16)*32 + slot];
#pragma unroll
    for (int nc = 0; nc < 4; ++nc) bfv[nc] = *(const short8*)&SB[(brow + nc*16)*32 + slot];
    if (t < 30){ STGA(t+2, nstg); STGB(t+2, nstg); }
    __builtin_amdgcn_s_setprio(1);
#pragma unroll
    for (int mi = 0; mi < 4; ++mi)
#pragma unroll
      for (int nc = 0; nc < 4; ++nc)
        acc[mi][nc] = MFMA16(af[mi], bfv[nc], acc[mi][nc]);
    __builtin_amdgcn_s_setprio(0);
    if (t < 30)       asm volatile("s_waitcnt vmcnt(3)" ::: "memory");
    else if (t == 30) asm volatile("s_waitcnt vmcnt(0)" ::: "memory");
    __builtin_amdgcn_s_barrier();
    buf = (buf >= 2) ? 0 : buf + 1;
  }
#undef STGA
#undef STGB

  const int colBase = n0 + (wn << 6) + lr;
#pragma unroll
  for (int mi = 0; mi < 4; ++mi){
    const int row0 = m0 + (wm << 6) + mi*16 + lg*4;
#pragma unroll
    for (int nc = 0; nc < 4; ++nc){
      const int col = colBase + nc*16;
      const float bvv = bias[col];
#pragma unroll
      for (int i = 0; i < 4; ++i)
        Cout[(long)(row0 + i) * 1024 + col] = acc[mi][nc][i] + bvv;
    }
  }
}

// ---------------- flash attention (causal), 8-wave block, KBLK=64 ----------------
__global__ __launch_bounds__(512, 4) void attn(
    const ushort_t* __restrict__ Qb, const ushort_t* __restrict__ Kb,
    const ushort_t* __restrict__ Vt, ushort_t* __restrict__ yb){
  __shared__ __align__(16) ushort_t Ks[2][4096];   // [64 key][64 d]
  __shared__ __align__(16) ushort_t Vs[2][4096];   // [64 d][64 k]
  const int tid = threadIdx.x;
  const int w = tid >> 6, l = tid & 63;
  const int lq = l & 31;
  const int hi = l >> 5;
  const int xcd = blockIdx.x & 7;
  const int idx = blockIdx.x >> 3;          // 0..63
  const int hi5 = idx >> 5;                 // 0/1
  const int bh  = (xcd << 3) + ((idx >> 3) & 3) + hi5 * 4;
  const int qj  = hi5 ? (idx & 7) : 7 - (idx & 7);
  const int qc = (qj << 3) + w;
  const int q0 = qc << 5;
  const int wkt = qc >> 1;                  // wave's diagonal 64-key tile
  const int p   = qc & 1;                   // which ksub holds the diagonal
  const int ktmax = (qj << 2) + 3;          // block's last 64-key tile
  const ushort_t* Qh = Qb + (long)bh * 131072;
  const ushort_t* Kh = Kb + (long)bh * 131072;
  const ushort_t* Vth = Vt + (long)bh * 131072;
  const int h8 = hi * 8;

  const ushort_t* qp = &Qh[(long)(q0 + lq) * 64 + h8];
  short8 qf0 = *(const short8*)(qp);
  short8 qf1 = *(const short8*)(qp + 16);
  short8 qf2 = *(const short8*)(qp + 32);
  short8 qf3 = *(const short8*)(qp + 48);

  const int stg_is_v = (w >= 4);
  const int wg = stg_is_v ? (w - 4) : w;            // 0..3
  const int row0 = (wg << 3) + (l >> 3);            // 0..31
  const int c8 = (l & 7);
  const int cc = c8 ^ (row0 & 7);
  long src0, src1;
  if (!stg_is_v){
    src0 = ((long)row0 << 6) + (cc << 3);
    src1 = ((long)(row0 + 32) << 6) + (cc << 3);
  } else {
    src0 = ((long)row0 << 11) + (cc << 3);
    src1 = ((long)(row0 + 32) << 11) + (cc << 3);
  }
  const int dst0 = (wg << 9) + (l << 3);
  const int dst1 = 2048 + dst0;

  f32x16 o0 = {}, o1 = {};
  float lsum = 0.f;
  const float cl2 = 0.1803368801111204f;   // log2(e)/8

  if (!stg_is_v){ GL_LDS16(Kh + src0,  &Ks[0][dst0]); GL_LDS16(Kh + src1,  &Ks[0][dst1]); }
  else          { GL_LDS16(Vth + src0, &Vs[0][dst0]); GL_LDS16(Vth + src1, &Vs[0][dst1]); }

  int cur = 0;
  for (int kt = 0; kt <= ktmax; ++kt){
    if (kt < ktmax){
      const long k0n = (long)(kt + 1) << 6;
      if (!stg_is_v){
        GL_LDS16(Kh + (k0n << 6) + src0, &Ks[cur ^ 1][dst0]);
        GL_LDS16(Kh + (k0n << 6) + src1, &Ks[cur ^ 1][dst1]);
      } else {
        GL_LDS16(Vth + k0n + src0, &Vs[cur ^ 1][dst0]);
        GL_LDS16(Vth + k0n + src1, &Vs[cur ^ 1][dst1]);
      }
      asm volatile("s_waitcnt vmcnt(2)" ::: "memory");
    } else {
      asm volatile("s_waitcnt vmcnt(0)" ::: "memory");
    }
    __builtin_amdgcn_s_barrier();
    if (kt <= wkt){
      const bool diag = (kt == wkt);
      const int swl = lq & 7;
#pragma unroll
      for (int ksub = 0; ksub < 2; ++ksub){
        if (diag && ksub > p) continue;
        const ushort_t* kr = &Ks[cur][(ksub * 32 + lq) << 6];
        short8 kf0 = *(const short8*)&kr[((    hi) ^ swl) << 3];
        short8 kf1 = *(const short8*)&kr[((2 + hi) ^ swl) << 3];
        short8 kf2 = *(const short8*)&kr[((4 + hi) ^ swl) << 3];
        short8 kf3 = *(const short8*)&kr[((6 + hi) ^ swl) << 3];
        f32x16 s = {};
        s = MFMA32(kf0, qf0, s);
        s = MFMA32(kf1, qf1, s);
        s = MFMA32(kf2, qf2, s);
        s = MFMA32(kf3, qf3, s);
        if (diag && ksub == p){
#pragma unroll
          for (int r = 0; r < 16; ++r){
            const int rk = (r & 3) + 8 * (r >> 2) + 4 * hi;
            if (rk > lq) s[r] = -1e30f;
          }
        }
#pragma unroll
        for (int r = 0; r < 16; ++r) s[r] = __builtin_amdgcn_exp2f(__builtin_fmaf(s[r], cl2, -2.0f));
        {
          float t0 = (s[0] + s[1]) + (s[2] + s[3]);
          float t1 = (s[4] + s[5]) + (s[6] + s[7]);
          float t2 = (s[8] + s[9]) + (s[10] + s[11]);
          float t3 = (s[12] + s[13]) + (s[14] + s[15]);
          lsum += (t0 + t1) + (t2 + t3);
        }
        uint32 a0 = cvtpk_bf16(s[0], s[1]),  b0 = cvtpk_bf16(s[4], s[5]);
        uint32 a1 = cvtpk_bf16(s[2], s[3]),  b1 = cvtpk_bf16(s[6], s[7]);
        uint32 a2 = cvtpk_bf16(s[8], s[9]),  b2 = cvtpk_bf16(s[12], s[13]);
        uint32 a3 = cvtpk_bf16(s[10], s[11]),b3 = cvtpk_bf16(s[14], s[15]);
        plswap(a0, b0);
        plswap(a1, b1);
        plswap(a2, b2);
        plswap(a3, b3);
        u32x4 pc0 = {a0, a1, b0, b1};
        u32x4 pc1 = {a2, a3, b2, b3};
        short8 pb0 = __builtin_bit_cast(short8, pc0);
        short8 pb1 = __builtin_bit_cast(short8, pc1);
        const ushort_t* vrlo = &Vs[cur][lq << 6];
        const ushort_t* vrhi = &Vs[cur][(lq + 32) << 6];
        const int cbase = ksub << 2;
        short8 vf00 = *(const short8*)&vrlo[((cbase +     hi) ^ swl) << 3];
        short8 vf01 = *(const short8*)&vrlo[((cbase + 2 + hi) ^ swl) << 3];
        short8 vf10 = *(const short8*)&vrhi[((cbase +     hi) ^ swl) << 3];
        short8 vf11 = *(const short8*)&vrhi[((cbase + 2 + hi) ^ swl) << 3];
        o0 = MFMA32(vf00, pb0, o0);
        o0 = MFMA32(vf01, pb1, o0);
        o1 = MFMA32(vf10, pb0, o1);
        o1 = MFMA32(vf11, pb1, o1);
      }
    }
    __builtin_amdgcn_s_barrier();
    cur ^= 1;
  }
  lsum += __shfl_xor(lsum, 32);
  const float inv = 1.0f / lsum;
  const int b = bh >> 4, h = bh & 15;
  const int tok = q0 + lq;
  ushort_t* yrow = yb + (long)(b * 2048 + tok) * 1024 + h * 64;
#pragma unroll
  for (int g = 0; g < 4; ++g){
    short4v p0, p1;
#pragma unroll
    for (int j = 0; j < 4; ++j){
      p0[j] = (short)f2bf(o0[4*g + j] * inv);
      p1[j] = (short)f2bf(o1[4*g + j] * inv);
    }
    *(short4v*)&yrow[8*g + 4*hi]      = p0;
    *(short4v*)&yrow[32 + 8*g + 4*hi] = p1;
  }
}

// ---------------- launch ----------------
extern "C" void kernel_launch(void* const* d_in, const int* in_sizes, int n_in,
                              void* d_out, int out_size, void* d_ws, size_t ws_size,
                              hipStream_t stream){
  const float* x  = (const float*)d_in[0];
  const float* Wq = (const float*)d_in[1];
  const float* bq = (const float*)d_in[2];
  const float* Wk = (const float*)d_in[3];
  const float* bk = (const float*)d_in[4];
  const float* Wv = (const float*)d_in[5];
  const float* bv = (const float*)d_in[6];
  const float* Wo = (const float*)d_in[7];
  const float* bo = (const float*)d_in[8];
  char* ws = (char*)d_ws;
  ushort_t* xb   = (ushort_t*)(ws);                      // 16 MB; reused as yb after attn
  ushort_t* wqkv = (ushort_t*)(ws + 16777216);           // 6 MB (Q,K,V packed)
  ushort_t* wob  = (ushort_t*)(ws + 23068672);           // 2 MB
  float2*   tab  = (float2*)  (ws + 25165824);           // 512 KB
  ushort_t* Qb   = (ushort_t*)(ws + 25690112);           // 16 MB
  ushort_t* Kb   = (ushort_t*)(ws + 42467328);           // 16 MB
  ushort_t* Vt   = (ushort_t*)(ws + 59244544);           // 16 MB
  ushort_t* yb   = xb;

  convert_all<<<6400, 256, 0, stream>>>(x, Wq, Wk, Wv, Wo, xb, wqkv, wob, tab);
  gemm_qkv<<<768, 512, 0, stream>>>(xb, wqkv, bq, bk, bv, tab, Qb, Kb, Vt);
  attn<<<512, 512, 0, stream>>>(Qb, Kb, Vt, yb);
  gemm_out<<<256, 512, 0, stream>>>(yb, wob, bo, (float*)d_out);
}

// Round 14
// 149.306 us; speedup vs baseline: 1.1143x; 1.0046x over previous
//
#include <hip/hip_runtime.h>
#include <hip/hip_bf16.h>
#include <cstdint>

typedef __attribute__((ext_vector_type(8))) short short8;
typedef __attribute__((ext_vector_type(4))) short short4v;
typedef __attribute__((ext_vector_type(4))) float f32x4;
typedef __attribute__((ext_vector_type(16))) float f32x16;
typedef __attribute__((ext_vector_type(4))) unsigned int u32x4;
typedef unsigned short ushort_t;
typedef unsigned int uint32;

#define DEVI static __device__ __forceinline__

DEVI ushort_t f2bf(float f){
  uint32 u = __builtin_bit_cast(uint32, f);
  u += 0x7FFFu + ((u >> 16) & 1u);
  return (ushort_t)(u >> 16);
}
DEVI uint32 cvtpk_bf16(float lo, float hi){
  uint32 r;
  asm("v_cvt_pk_bf16_f32 %0, %1, %2" : "=v"(r) : "v"(lo), "v"(hi));
  return r;
}
DEVI void plswap(uint32& a, uint32& b){
  asm("v_permlane32_swap_b32 %0, %1" : "+v"(a), "+v"(b));
}

typedef __attribute__((address_space(1))) const uint32 g_u32;
typedef __attribute__((address_space(3))) uint32 l_u32;
#define GL_LDS16(gp, lp) __builtin_amdgcn_global_load_lds((g_u32*)(gp), (l_u32*)(lp), 16, 0, 0)

#define MFMA16(a, b, c) __builtin_amdgcn_mfma_f32_16x16x32_bf16(a, b, c, 0, 0, 0)
#define MFMA32(a, b, c) __builtin_amdgcn_mfma_f32_32x32x16_bf16(a, b, c, 0, 0, 0)

// ---------------- fp32 -> bf16 conversion + rope table ----------------
__global__ __launch_bounds__(256) void convert_all(
    const float* __restrict__ x, const float* __restrict__ wq, const float* __restrict__ wk,
    const float* __restrict__ wv, const float* __restrict__ wo,
    ushort_t* __restrict__ xb, ushort_t* __restrict__ wqkv, ushort_t* __restrict__ wob,
    float2* __restrict__ tab){
  int bid = blockIdx.x;
  if (bid >= 6144){
    const int idx = (bid - 6144) * 256 + threadIdx.x;    // 65536
    const int tok = idx >> 5, j = idx & 31;
    const float theta = exp2f(-(float)j * 0.4152410118609203f);   // log2(10000)/32
    const float ang = (float)(tok + 1) * theta;
    float s, c;
    sincosf(ang, &s, &c);
    tab[idx] = make_float2(c, s);
    return;
  }
  const float* src; ushort_t* dst; long base;
  if (bid < 4096){ src = x; dst = xb; base = (long)bid * 2048; }
  else {
    int r = bid - 4096; int sel = r >> 9; int o = r & 511;
    src = sel==0?wq: sel==1?wk: sel==2?wv: wo;
    dst = (sel<3) ? (wqkv + (long)sel * 1048576) : wob;
    base = (long)o * 2048;
  }
  long i = base + (long)threadIdx.x * 8;
  const float* p = src + i;
  float4 a = *(const float4*)p;
  float4 b = *(const float4*)(p + 4);
  short8 v;
  v[0]=(short)f2bf(a.x); v[1]=(short)f2bf(a.y); v[2]=(short)f2bf(a.z); v[3]=(short)f2bf(a.w);
  v[4]=(short)f2bf(b.x); v[5]=(short)f2bf(b.y); v[6]=(short)f2bf(b.z); v[7]=(short)f2bf(b.w);
  *(short8*)(dst + i) = v;
}

// ---------------- QKV GEMM, 256x128 tile, BK=32, tri-buffered, 1 barrier/tile ----------------
// (unchanged from r13: 72 KB LDS -> 2 blocks/CU)
__global__ __launch_bounds__(512, 2) void gemm_qkv(
    const ushort_t* __restrict__ A, const ushort_t* __restrict__ Bw,
    const float* __restrict__ bq, const float* __restrict__ bk, const float* __restrict__ bv,
    const float2* __restrict__ tab,
    ushort_t* __restrict__ Qb, ushort_t* __restrict__ Kb, ushort_t* __restrict__ Vt){
  __shared__ __align__(16) ushort_t S[36864];   // 72 KB: 3 bufs x (A 16KB | B 8KB)
  const int tid = threadIdx.x;
  const int w = tid >> 6, l = tid & 63, lr = l & 15, lg = l >> 4;
  const int wm = w >> 1, wn = w & 1;            // 4M x 2N
  const int xcd = blockIdx.x & 7;
  const int l9  = blockIdx.x >> 3;              // 0..95
  const int bg  = l9 >> 5;                      // 0..2
  const int rem = l9 & 31;
  const int bm  = ((xcd & 3) << 3) + (rem >> 2);
  const int bn  = ((xcd >> 2) * 12) + (bg << 2) + (rem & 3);
  const int m0 = bm << 8, n0 = bn << 7;
  const int rbase = tid >> 2;
  const int swzk = (tid & 3) ^ ((tid >> 3) & 3);
  const ushort_t* aS = A  + (long)(m0 + rbase) * 1024 + swzk * 8;
  const ushort_t* bS = Bw + (long)(n0 + rbase) * 1024 + swzk * 8;
  const int slot = (lg ^ ((lr >> 1) & 3)) << 3;
  const int arow = wm * 64 + lr;
  const int brow = wn * 64 + lr;
  f32x4 acc[4][4] = {};

#define STGA(t, bf_) do{ \
    const ushort_t* _s = aS + (long)(t)*32; \
    ushort_t* _d = &S[(bf_)*12288 + tid*8]; \
    GL_LDS16(_s,          _d); \
    GL_LDS16(_s + 131072, _d + 4096); }while(0)
#define STGB(t, bf_) do{ \
    GL_LDS16(bS + (long)(t)*32, &S[(bf_)*12288 + 8192 + tid*8]); }while(0)

  STGA(0,0); STGB(0,0);
  STGA(1,1); STGB(1,1);
  asm volatile("s_waitcnt vmcnt(3)" ::: "memory");
  __builtin_amdgcn_s_barrier();

  int buf = 0;
  for (int t = 0; t < 32; ++t){
    const int nstg = (buf >= 1) ? buf - 1 : 2;     // (t+2)%3
    const ushort_t* SA = &S[buf * 12288];
    const ushort_t* SB = &S[buf * 12288 + 8192];
    short8 af[4], bfv[4];
#pragma unroll
    for (int mi = 0; mi < 4; ++mi) af[mi]  = *(const short8*)&SA[(arow + mi*16)*32 + slot];
#pragma unroll
    for (int nc = 0; nc < 4; ++nc) bfv[nc] = *(const short8*)&SB[(brow + nc*16)*32 + slot];
    if (t < 30){ STGA(t+2, nstg); STGB(t+2, nstg); }
    __builtin_amdgcn_s_setprio(1);
#pragma unroll
    for (int mi = 0; mi < 4; ++mi)
#pragma unroll
      for (int nc = 0; nc < 4; ++nc)
        acc[mi][nc] = MFMA16(af[mi], bfv[nc], acc[mi][nc]);
    __builtin_amdgcn_s_setprio(0);
    if (t < 30)       asm volatile("s_waitcnt vmcnt(3)" ::: "memory");
    else if (t == 30) asm volatile("s_waitcnt vmcnt(0)" ::: "memory");
    __builtin_amdgcn_s_barrier();
    buf = (buf >= 2) ? 0 : buf + 1;
  }
#undef STGA
#undef STGB

  const int colX = n0 + (wn << 6);
  const int sel = colX >> 10;                // 0=Q 1=K 2=V
  const int h = (colX >> 6) & 15;
  const int cB = (colX & 1023) + lr;
  if (sel < 2){
    ushort_t* dst = sel ? Kb : Qb;
    const float* bp = sel ? bk : bq;
    const float bvs[4] = {bp[cB], bp[cB+16], bp[cB+32], bp[cB+48]};
#pragma unroll
    for (int mi = 0; mi < 4; ++mi){
      const int row0 = m0 + (wm << 6) + mi*16 + lg*4;
#pragma unroll
      for (int i = 0; i < 4; ++i){
        const int r = row0 + i;
        const int b = r >> 11, tok = r & 2047;
#pragma unroll
        for (int nc = 0; nc < 2; ++nc){
          const int j = nc*16 + lr;
          const float2 cs = tab[tok*32 + j];
          const float v0 = acc[mi][nc][i]   + bvs[nc];
          const float v1 = acc[mi][nc+2][i] + bvs[nc+2];
          const long base = (((long)((b<<4) + h) * 2048 + tok) << 6) + j;
          dst[base]      = f2bf(v0 * cs.x - v1 * cs.y);
          dst[base + 32] = f2bf(v1 * cs.x + v0 * cs.y);
        }
      }
    }
  } else {
    // V: LDS transpose -> coalesced Vt writes (wave-private 4608-ushort region)
    const float bvs[4] = {bv[cB], bv[cB+16], bv[cB+32], bv[cB+48]};
    ushort_t* T = &S[w * 4608];
#pragma unroll
    for (int nc = 0; nc < 4; ++nc){
      const int d = nc*16 + lr;
      const int dx = d & 7;
#pragma unroll
      for (int mi = 0; mi < 4; ++mi){
        const int col = mi*16 + lg*4;
        const int scol = (((col >> 3) ^ dx) << 3) + (col & 7);
        const uint32 p0 = cvtpk_bf16(acc[mi][nc][0] + bvs[nc], acc[mi][nc][1] + bvs[nc]);
        const uint32 p1 = cvtpk_bf16(acc[mi][nc][2] + bvs[nc], acc[mi][nc][3] + bvs[nc]);
        uint32* dp = (uint32*)&T[d*72 + scol];
        dp[0] = p0; dp[1] = p1;
      }
    }
    const int rowbase = m0 + (wm << 6);
    const int b = rowbase >> 11;
    const int tok0 = rowbase & 2047;
    ushort_t* vbase = Vt + (((long)((b << 4) + h)) << 17);   // *64*2048
    const int dl = l >> 3, c8 = l & 7;
#pragma unroll
    for (int it = 0; it < 8; ++it){
      const int d = dl + it*8;
      short8 v = *(const short8*)&T[d*72 + ((c8 ^ (d & 7)) << 3)];
      *(short8*)&vbase[((long)d << 11) + tok0 + (c8 << 3)] = v;
    }
  }
}

// ---------------- output GEMM, 128x128 tile, BK=32, tri-buffered, 2 blocks/CU ----------------
// 256 threads, 4 waves (2M x 2N, wave = 64x64). LDS 48 KB; grid 512 = 2/CU resident.
// 4 loads/thread/tile staged 2 ahead; ONE vmcnt(4) + ONE barrier per tile.
__global__ __launch_bounds__(256, 3) void gemm_out(
    const ushort_t* __restrict__ A, const ushort_t* __restrict__ Bw,
    const float* __restrict__ bias, float* __restrict__ Cout){
  __shared__ __align__(16) ushort_t S[24576];   // 48 KB: 3 bufs x (A 8KB | B 8KB)
  const int tid = threadIdx.x;
  const int w = tid >> 6, l = tid & 63, lr = l & 15, lg = l >> 4;
  const int wm = w >> 1, wn = w & 1;
  const int xcd = blockIdx.x & 7;
  const int l6  = blockIdx.x >> 3;              // 0..63
  const int bm  = (xcd << 3) + (l6 >> 3);       // 0..63
  const int bn  = l6 & 7;
  const int m0 = bm << 7, n0 = bn << 7;
  const int rbase = tid >> 2;                   // 0..63 (+64 for 2nd load)
  const int swzk = (tid & 3) ^ ((tid >> 3) & 3);
  const ushort_t* aS = A  + (long)(m0 + rbase) * 1024 + swzk * 8;
  const ushort_t* bS = Bw + (long)(n0 + rbase) * 1024 + swzk * 8;
  const int slot = (lg ^ ((lr >> 1) & 3)) << 3;
  const int arow = wm * 64 + lr;
  const int brow = wn * 64 + lr;
  f32x4 acc[4][4] = {};

#define STGA(t, bf_) do{ \
    const ushort_t* _s = aS + (long)(t)*32; \
    ushort_t* _d = &S[(bf_)*8192 + tid*8]; \
    GL_LDS16(_s,         _d); \
    GL_LDS16(_s + 65536, _d + 2048); }while(0)
#define STGB(t, bf_) do{ \
    const ushort_t* _s = bS + (long)(t)*32; \
    ushort_t* _d = &S[(bf_)*8192 + 4096 + tid*8]; \
    GL_LDS16(_s,         _d); \
    GL_LDS16(_s + 65536, _d + 2048); }while(0)

  STGA(0,0); STGB(0,0);
  STGA(1,1); STGB(1,1);
  asm volatile("s_waitcnt vmcnt(4)" ::: "memory");
  __builtin_amdgcn_s_barrier();

  int buf = 0;
  for (int t = 0; t < 32; ++t){
    const int nstg = (buf >= 1) ? buf - 1 : 2;
    const ushort_t* SA = &S[buf * 8192];
    const ushort_t* SB = &S[buf * 8192 + 4096];
    short8 af[4], bfv[4];
#pragma unroll
    for (int mi = 0; mi < 4; ++mi) af[mi]  = *(const short8*)&SA[(arow + mi*16)*32 + slot];
#pragma unroll
    for (int nc = 0; nc < 4; ++nc) bfv[nc] = *(const short8*)&SB[(brow + nc*16)*32 + slot];
    if (t < 30){ STGA(t+2, nstg); STGB(t+2, nstg); }
    __builtin_amdgcn_s_setprio(1);
#pragma unroll
    for (int mi = 0; mi < 4; ++mi)
#pragma unroll
      for (int nc = 0; nc < 4; ++nc)
        acc[mi][nc] = MFMA16(af[mi], bfv[nc], acc[mi][nc]);
    __builtin_amdgcn_s_setprio(0);
    if (t < 30)       asm volatile("s_waitcnt vmcnt(4)" ::: "memory");  // tile t+1 resident
    else if (t == 30) asm volatile("s_waitcnt vmcnt(0)" ::: "memory");
    __builtin_amdgcn_s_barrier();
    buf = (buf >= 2) ? 0 : buf + 1;
  }
#undef STGA
#undef STGB

  const int colBase = n0 + (wn << 6) + lr;
#pragma unroll
  for (int mi = 0; mi < 4; ++mi){
    const int row0 = m0 + (wm << 6) + mi*16 + lg*4;
#pragma unroll
    for (int nc = 0; nc < 4; ++nc){
      const int col = colBase + nc*16;
      const float bvv = bias[col];
#pragma unroll
      for (int i = 0; i < 4; ++i)
        Cout[(long)(row0 + i) * 1024 + col] = acc[mi][nc][i] + bvv;
    }
  }
}

// ---------------- flash attention (causal), 8-wave block, KBLK=64 ----------------
__global__ __launch_bounds__(512, 4) void attn(
    const ushort_t* __restrict__ Qb, const ushort_t* __restrict__ Kb,
    const ushort_t* __restrict__ Vt, ushort_t* __restrict__ yb){
  __shared__ __align__(16) ushort_t Ks[2][4096];   // [64 key][64 d]
  __shared__ __align__(16) ushort_t Vs[2][4096];   // [64 d][64 k]
  const int tid = threadIdx.x;
  const int w = tid >> 6, l = tid & 63;
  const int lq = l & 31;
  const int hi = l >> 5;
  const int xcd = blockIdx.x & 7;
  const int idx = blockIdx.x >> 3;          // 0..63
  const int hi5 = idx >> 5;                 // 0/1
  const int bh  = (xcd << 3) + ((idx >> 3) & 3) + hi5 * 4;
  const int qj  = hi5 ? (idx & 7) : 7 - (idx & 7);
  const int qc = (qj << 3) + w;
  const int q0 = qc << 5;
  const int wkt = qc >> 1;
  const int p   = qc & 1;
  const int ktmax = (qj << 2) + 3;
  const ushort_t* Qh = Qb + (long)bh * 131072;
  const ushort_t* Kh = Kb + (long)bh * 131072;
  const ushort_t* Vth = Vt + (long)bh * 131072;
  const int h8 = hi * 8;

  const ushort_t* qp = &Qh[(long)(q0 + lq) * 64 + h8];
  short8 qf0 = *(const short8*)(qp);
  short8 qf1 = *(const short8*)(qp + 16);
  short8 qf2 = *(const short8*)(qp + 32);
  short8 qf3 = *(const short8*)(qp + 48);

  const int stg_is_v = (w >= 4);
  const int wg = stg_is_v ? (w - 4) : w;            // 0..3
  const int row0 = (wg << 3) + (l >> 3);            // 0..31
  const int c8 = (l & 7);
  const int cc = c8 ^ (row0 & 7);
  long src0, src1;
  if (!stg_is_v){
    src0 = ((long)row0 << 6) + (cc << 3);
    src1 = ((long)(row0 + 32) << 6) + (cc << 3);
  } else {
    src0 = ((long)row0 << 11) + (cc << 3);
    src1 = ((long)(row0 + 32) << 11) + (cc << 3);
  }
  const int dst0 = (wg << 9) + (l << 3);
  const int dst1 = 2048 + dst0;

  f32x16 o0 = {}, o1 = {};
  float lsum = 0.f;
  const float cl2 = 0.1803368801111204f;   // log2(e)/8

  if (!stg_is_v){ GL_LDS16(Kh + src0,  &Ks[0][dst0]); GL_LDS16(Kh + src1,  &Ks[0][dst1]); }
  else          { GL_LDS16(Vth + src0, &Vs[0][dst0]); GL_LDS16(Vth + src1, &Vs[0][dst1]); }

  int cur = 0;
  for (int kt = 0; kt <= ktmax; ++kt){
    if (kt < ktmax){
      const long k0n = (long)(kt + 1) << 6;
      if (!stg_is_v){
        GL_LDS16(Kh + (k0n << 6) + src0, &Ks[cur ^ 1][dst0]);
        GL_LDS16(Kh + (k0n << 6) + src1, &Ks[cur ^ 1][dst1]);
      } else {
        GL_LDS16(Vth + k0n + src0, &Vs[cur ^ 1][dst0]);
        GL_LDS16(Vth + k0n + src1, &Vs[cur ^ 1][dst1]);
      }
      asm volatile("s_waitcnt vmcnt(2)" ::: "memory");
    } else {
      asm volatile("s_waitcnt vmcnt(0)" ::: "memory");
    }
    __builtin_amdgcn_s_barrier();
    if (kt <= wkt){
      const bool diag = (kt == wkt);
      const int swl = lq & 7;
#pragma unroll
      for (int ksub = 0; ksub < 2; ++ksub){
        if (diag && ksub > p) continue;
        const ushort_t* kr = &Ks[cur][(ksub * 32 + lq) << 6];
        short8 kf0 = *(const short8*)&kr[((    hi) ^ swl) << 3];
        short8 kf1 = *(const short8*)&kr[((2 + hi) ^ swl) << 3];
        short8 kf2 = *(const short8*)&kr[((4 + hi) ^ swl) << 3];
        short8 kf3 = *(const short8*)&kr[((6 + hi) ^ swl) << 3];
        f32x16 s = {};
        s = MFMA32(kf0, qf0, s);
        s = MFMA32(kf1, qf1, s);
        s = MFMA32(kf2, qf2, s);
        s = MFMA32(kf3, qf3, s);
        if (diag && ksub == p){
#pragma unroll
          for (int r = 0; r < 16; ++r){
            const int rk = (r & 3) + 8 * (r >> 2) + 4 * hi;
            if (rk > lq) s[r] = -1e30f;
          }
        }
#pragma unroll
        for (int r = 0; r < 16; ++r) s[r] = __builtin_amdgcn_exp2f(__builtin_fmaf(s[r], cl2, -2.0f));
        {
          float t0 = (s[0] + s[1]) + (s[2] + s[3]);
          float t1 = (s[4] + s[5]) + (s[6] + s[7]);
          float t2 = (s[8] + s[9]) + (s[10] + s[11]);
          float t3 = (s[12] + s[13]) + (s[14] + s[15]);
          lsum += (t0 + t1) + (t2 + t3);
        }
        uint32 a0 = cvtpk_bf16(s[0], s[1]),  b0 = cvtpk_bf16(s[4], s[5]);
        uint32 a1 = cvtpk_bf16(s[2], s[3]),  b1 = cvtpk_bf16(s[6], s[7]);
        uint32 a2 = cvtpk_bf16(s[8], s[9]),  b2 = cvtpk_bf16(s[12], s[13]);
        uint32 a3 = cvtpk_bf16(s[10], s[11]),b3 = cvtpk_bf16(s[14], s[15]);
        plswap(a0, b0);
        plswap(a1, b1);
        plswap(a2, b2);
        plswap(a3, b3);
        u32x4 pc0 = {a0, a1, b0, b1};
        u32x4 pc1 = {a2, a3, b2, b3};
        short8 pb0 = __builtin_bit_cast(short8, pc0);
        short8 pb1 = __builtin_bit_cast(short8, pc1);
        const ushort_t* vrlo = &Vs[cur][lq << 6];
        const ushort_t* vrhi = &Vs[cur][(lq + 32) << 6];
        const int cbase = ksub << 2;
        short8 vf00 = *(const short8*)&vrlo[((cbase +     hi) ^ swl) << 3];
        short8 vf01 = *(const short8*)&vrlo[((cbase + 2 + hi) ^ swl) << 3];
        short8 vf10 = *(const short8*)&vrhi[((cbase +     hi) ^ swl) << 3];
        short8 vf11 = *(const short8*)&vrhi[((cbase + 2 + hi) ^ swl) << 3];
        o0 = MFMA32(vf00, pb0, o0);
        o0 = MFMA32(vf01, pb1, o0);
        o1 = MFMA32(vf10, pb0, o1);
        o1 = MFMA32(vf11, pb1, o1);
      }
    }
    __builtin_amdgcn_s_barrier();
    cur ^= 1;
  }
  lsum += __shfl_xor(lsum, 32);
  const float inv = 1.0f / lsum;
  const int b = bh >> 4, h = bh & 15;
  const int tok = q0 + lq;
  ushort_t* yrow = yb + (long)(b * 2048 + tok) * 1024 + h * 64;
#pragma unroll
  for (int g = 0; g < 4; ++g){
    short4v p0, p1;
#pragma unroll
    for (int j = 0; j < 4; ++j){
      p0[j] = (short)f2bf(o0[4*g + j] * inv);
      p1[j] = (short)f2bf(o1[4*g + j] * inv);
    }
    *(short4v*)&yrow[8*g + 4*hi]      = p0;
    *(short4v*)&yrow[32 + 8*g + 4*hi] = p1;
  }
}

// ---------------- launch ----------------
extern "C" void kernel_launch(void* const* d_in, const int* in_sizes, int n_in,
                              void* d_out, int out_size, void* d_ws, size_t ws_size,
                              hipStream_t stream){
  const float* x  = (const float*)d_in[0];
  const float* Wq = (const float*)d_in[1];
  const float* bq = (const float*)d_in[2];
  const float* Wk = (const float*)d_in[3];
  const float* bk = (const float*)d_in[4];
  const float* Wv = (const float*)d_in[5];
  const float* bv = (const float*)d_in[6];
  const float* Wo = (const float*)d_in[7];
  const float* bo = (const float*)d_in[8];
  char* ws = (char*)d_ws;
  ushort_t* xb   = (ushort_t*)(ws);                      // 16 MB; reused as yb after attn
  ushort_t* wqkv = (ushort_t*)(ws + 16777216);           // 6 MB (Q,K,V packed)
  ushort_t* wob  = (ushort_t*)(ws + 23068672);           // 2 MB
  float2*   tab  = (float2*)  (ws + 25165824);           // 512 KB
  ushort_t* Qb   = (ushort_t*)(ws + 25690112);           // 16 MB
  ushort_t* Kb   = (ushort_t*)(ws + 42467328);           // 16 MB
  ushort_t* Vt   = (ushort_t*)(ws + 59244544);           // 16 MB
  ushort_t* yb   = xb;

  convert_all<<<6400, 256, 0, stream>>>(x, Wq, Wk, Wv, Wo, xb, wqkv, wob, tab);
  gemm_qkv<<<768, 512, 0, stream>>>(xb, wqkv, bq, bk, bv, tab, Qb, Kb, Vt);
  attn<<<512, 512, 0, stream>>>(Qb, Kb, Vt, yb);
  gemm_out<<<512, 256, 0, stream>>>(yb, wob, bo, (float*)d_out);
}